// Round 5
// baseline (242.744 us; speedup 1.0000x reference)
//
#include <hip/hip_runtime.h>
#include <hip/hip_bf16.h>

#define N_IMG 4
#define C_CH 256
#define H_DIM 64
#define W_DIM 64
#define HW 4096
#define NCLASS 20
#define NHEADS 4
#define HD 64   // channels per head

typedef __attribute__((ext_vector_type(8))) short short8;
typedef __attribute__((ext_vector_type(4))) float f32x4;

__device__ __forceinline__ ushort f2bf(float f) {
    unsigned u = __float_as_uint(f);
    u += 0x7FFFu + ((u >> 16) & 1u);   // RNE
    return (ushort)(u >> 16);
}

// ---------------------------------------------------------------------------
__global__ void k_init(unsigned* mmax) {
    if (threadIdx.x < N_IMG) mmax[threadIdx.x] = 0u;
}

// mask pre-normalization + per-image max; 256 threads: 4 c-chunks x 64 w
__global__ __launch_bounds__(256) void k_mask_m(const float* __restrict__ feats,
                         const float* __restrict__ wgap,
                         const int* __restrict__ label,
                         float* __restrict__ mask, unsigned* __restrict__ mmax) {
    int b = blockIdx.x;            // N*H = 256
    int n = b >> 6, h = b & 63;
    int t = threadIdx.x;
    int w = t & 63, cq = t >> 6;
    __shared__ float wrow[C_CH];
    __shared__ float part[4][64];
    int lab = label[n];
    wrow[t] = wgap[lab * C_CH + t];
    __syncthreads();
    const float* fp = feats + ((size_t)(n * C_CH + cq * 64)) * HW + h * W_DIM + w;
    float acc = 0.f;
    for (int c = 0; c < 64; c++) acc += fp[(size_t)c * HW] * wrow[cq * 64 + c];
    part[cq][w] = acc;
    __syncthreads();
    if (cq == 0) {
        float m = fmaxf(part[0][w] + part[1][w] + part[2][w] + part[3][w], 0.f);
        mask[n * HW + h * W_DIM + w] = m;
        for (int off = 32; off; off >>= 1) m = fmaxf(m, __shfl_down(m, off, 64));
        if (w == 0) atomicMax(&mmax[n], __float_as_uint(m));
    }
}

__global__ void k_mask_norm(float* __restrict__ mask, const unsigned* __restrict__ mmax) {
    int i = blockIdx.x * 256 + threadIdx.x;
    if (i < N_IMG * HW) {
        int n = i / HW;
        float mx = fmaxf(__uint_as_float(mmax[n]), 1.0f);
        mask[i] = mask[i] / mx;
    }
}

// per-(n,c) plane sum for GAP on feats
__global__ void k_plane_sum(const float* __restrict__ x, float* __restrict__ S) {
    int nc = blockIdx.x;
    const float* p = x + (size_t)nc * HW;
    float s = 0.f;
    for (int i = threadIdx.x; i < HW; i += 256) s += p[i];
    __shared__ float red[4];
    for (int off = 32; off; off >>= 1) s += __shfl_down(s, off, 64);
    int wid = threadIdx.x >> 6;
    if ((threadIdx.x & 63) == 0) red[wid] = s;
    __syncthreads();
    if (threadIdx.x == 0) S[nc] = red[0] + red[1] + red[2] + red[3];
}

__global__ void k_pred(const float* __restrict__ S, const float* __restrict__ wg,
                       float* __restrict__ out) {
    int idx = threadIdx.x;
    if (idx < N_IMG * NCLASS) {
        int n = idx / NCLASS, k = idx % NCLASS;
        float s = 0.f;
        for (int c = 0; c < C_CH; c++) s += wg[k * C_CH + c] * S[n * C_CH + c];
        out[idx] = s * (1.0f / HW);
    }
}

// ---------------------------------------------------------------------------
// infusion attention scores (5x5, dil 3): 16-wave structure, writes normalized
// att to global. att[((a*25+k)*N + n)*HW + h*64 + w]
__global__ __launch_bounds__(1024) void k_att_inf(
    const float* __restrict__ patch_t,   // Q (im2col side)
    const float* __restrict__ center_t,  // K (center side)
    float* __restrict__ att) {
    int b = blockIdx.x;                 // N*H = 256
    int n = b >> 6, h = b & 63;
    int t = threadIdx.x;
    int w = t & 63;
    int a = (t >> 6) & 3;
    int cq = t >> 8;                    // channel quarter
    __shared__ float att_s[4][25][64];  // 25.6 KB
    for (int i = t; i < 4 * 25 * 64; i += 1024) ((float*)att_s)[i] = 0.f;
    __syncthreads();

    int off[25];
#pragma unroll
    for (int k = 0; k < 25; k++) {
        int y = h + (k / 5 - 2) * 3, x = w + (k % 5 - 2) * 3;
        off[k] = (y >= 0 && y < 64 && x >= 0 && x < 64) ? y * 64 + x : -1;
    }
    float s[25];
#pragma unroll
    for (int k = 0; k < 25; k++) s[k] = 0.f;
    const float* cp = center_t + ((size_t)(n * C_CH + a * HD + cq * 16)) * HW + h * W_DIM + w;
    const float* pp = patch_t + ((size_t)(n * C_CH + a * HD + cq * 16)) * HW;
    for (int c = 0; c < 16; c++) {
        float cen = cp[(size_t)c * HW];
        const float* pc = pp + (size_t)c * HW;
#pragma unroll
        for (int k = 0; k < 25; k++) {
            float pv = (off[k] >= 0) ? pc[off[k]] : 0.f;
            s[k] += pv * cen;
        }
    }
#pragma unroll
    for (int k = 0; k < 25; k++) atomicAdd(&att_s[a][k][w], s[k]);
    __syncthreads();
    if (cq == 0) {
        float v[25];
        float mx = -1e30f;
#pragma unroll
        for (int k = 0; k < 25; k++) { v[k] = att_s[a][k][w]; mx = fmaxf(mx, v[k]); }
        float sum = 0.f;
#pragma unroll
        for (int k = 0; k < 25; k++) { v[k] = __expf(v[k] - mx); sum += v[k]; }
        float inv = 1.0f / sum;
#pragma unroll
        for (int k = 0; k < 25; k++)
            att[((size_t)(a * 25 + k) * N_IMG + n) * HW + h * 64 + w] = v[k] * inv;
    }
}

// W_a[n,y,x] = sum_k att[a,k,(y-dy_k, x-dx_k)] (scatter form of the GAP sum)
__global__ __launch_bounds__(256) void k_scatter_w(const float* __restrict__ att,
                                                   float* __restrict__ W) {
    int b = blockIdx.x;   // n*64 + y
    int n = b >> 6, y = b & 63;
    int t = threadIdx.x;
    int x = t & 63, a = t >> 6;
    float s = 0.f;
#pragma unroll
    for (int k = 0; k < 25; k++) {
        int sy = y - (k / 5 - 2) * 3, sx = x - (k % 5 - 2) * 3;
        if (sy >= 0 && sy < 64 && sx >= 0 && sx < 64)
            s += att[((size_t)(a * 25 + k) * N_IMG + n) * HW + sy * 64 + sx];
    }
    W[((size_t)a * N_IMG + n) * HW + y * 64 + x] = s;
}

// S_r[n,c] = sum_px feats[n,c,px] * W[a(c),n,px]  (weighted plane sum, f32x4)
__global__ __launch_bounds__(256) void k_wsum(const float* __restrict__ V,
                                              const float* __restrict__ W,
                                              float* __restrict__ S) {
    int nc = blockIdx.x;               // n*256 + c
    int n = nc >> 8, c = nc & 255;
    int a = c >> 6;
    const f32x4* p4 = (const f32x4*)(V + (size_t)nc * HW);
    const f32x4* w4 = (const f32x4*)(W + ((size_t)a * N_IMG + n) * HW);
    f32x4 a4 = (f32x4){0.f, 0.f, 0.f, 0.f};
    for (int i = threadIdx.x; i < HW / 4; i += 256) {
        f32x4 u = p4[i], v = w4[i];
        a4 += u * v;
    }
    float s = a4[0] + a4[1] + a4[2] + a4[3];
    __shared__ float red[4];
    for (int off = 32; off; off >>= 1) s += __shfl_down(s, off, 64);
    int wid = threadIdx.x >> 6;
    if ((threadIdx.x & 63) == 0) red[wid] = s;
    __syncthreads();
    if (threadIdx.x == 0) S[nc] = red[0] + red[1] + red[2] + red[3];
}

// ---------------------------------------------------------------------------
// diffusion attention scores (3x3, dil 6), masked — 16-wave version
__global__ __launch_bounds__(1024) void k_att_dif(
    const float* __restrict__ patch_t,   // K
    const float* __restrict__ center_t,  // Q
    const float* __restrict__ mask, float* __restrict__ att) {
    int b = blockIdx.x;                 // N*H = 256
    int n = b >> 6, h = b & 63;
    int t = threadIdx.x;
    int w = t & 63;
    int a = (t >> 6) & 3;
    int cq = t >> 8;
    __shared__ float att_s[4][9][64];   // 9.2 KB
    for (int i = t; i < 4 * 9 * 64; i += 1024) ((float*)att_s)[i] = 0.f;
    __syncthreads();

    int off[9];
#pragma unroll
    for (int k = 0; k < 9; k++) {
        int y = h + (k / 3 - 1) * 6, x = w + (k % 3 - 1) * 6;
        off[k] = (y >= 0 && y < 64 && x >= 0 && x < 64) ? y * 64 + x : -1;
    }
    float s[9];
#pragma unroll
    for (int k = 0; k < 9; k++) s[k] = 0.f;
    const float* cp = center_t + ((size_t)(n * C_CH + a * HD + cq * 16)) * HW + h * W_DIM + w;
    const float* pp = patch_t + ((size_t)(n * C_CH + a * HD + cq * 16)) * HW;
    for (int c = 0; c < 16; c++) {
        float cen = cp[(size_t)c * HW];
        const float* pc = pp + (size_t)c * HW;
#pragma unroll
        for (int k = 0; k < 9; k++) {
            float pv = (off[k] >= 0) ? pc[off[k]] : 0.f;
            s[k] += pv * cen;
        }
    }
#pragma unroll
    for (int k = 0; k < 9; k++) atomicAdd(&att_s[a][k][w], s[k]);
    __syncthreads();
    if (cq == 0) {
        float v[9];
        float mx = -1e30f;
#pragma unroll
        for (int k = 0; k < 9; k++) { v[k] = att_s[a][k][w]; mx = fmaxf(mx, v[k]); }
        float sum = 0.f;
#pragma unroll
        for (int k = 0; k < 9; k++) { v[k] = __expf(v[k] - mx); sum += v[k]; }
        float mm = mask[n * HW + h * W_DIM + w] / sum;
#pragma unroll
        for (int k = 0; k < 9; k++)
            att[((size_t)(a * 9 + k) * N_IMG + n) * HW + h * W_DIM + w] = v[k] * mm;
    }
}

// ---------------------------------------------------------------------------
// Zero only the halo border of xinp [4][66][66][512] (interior is fully
// rewritten by k_prep_fused every launch). 260 segments of 512 ushorts per n.
__global__ __launch_bounds__(256) void k_zero_border(ushort* __restrict__ xinp) {
    int b = blockIdx.x;            // n*260 + seg
    int n = b / 260, seg = b % 260;
    size_t base;
    if (seg < 66)       base = ((size_t)(n * 66 + 0) * 66 + seg) * 512;
    else if (seg < 132) base = ((size_t)(n * 66 + 65) * 66 + (seg - 66)) * 512;
    else {
        int c = seg - 132;
        int r = 1 + (c >> 1), x = (c & 1) ? 65 : 0;
        base = ((size_t)(n * 66 + r) * 66 + x) * 512;
    }
    ((unsigned*)(xinp + base))[threadIdx.x] = 0u;   // 256 x 4B = 1024B = 512 ushorts
}

// ---------------------------------------------------------------------------
// FUSED conv-input prep, round-13: latency-oriented restructure.
// Grid (64 y, 4 n, 4 c-quarter) = 1024 blocks, 256 thr (x=lane, wave=32ch).
// cq 0,1: feats*mask (channels cq*128..+128); cq 2,3: diffusion gather
// (channels 256+(cq-2)*128..+128, 2 heads). All global loads wave-coalesced
// 256B; 8 bf16 packed per ds_write_b128; write 256B/px contiguous.
__global__ __launch_bounds__(256) void k_prep_fused(
    const float* __restrict__ feats, const float* __restrict__ mask,
    const float* __restrict__ att, ushort* __restrict__ xinp) {
    int y = blockIdx.x, n = blockIdx.y, cq = blockIdx.z;
    int t = threadIdx.x;
    int x = t & 63, wv = t >> 6;      // 4 waves x 32 channels
    __shared__ ushort sx2[64][130];   // 16.6 KB (odd dword stride: conflict-free)
    __shared__ float att_s[2][9][64]; // 4.6 KB (2 heads for this quarter)

    if (cq >= 2) {
        for (int idx = t; idx < 2 * 9 * 64; idx += 256) {
            int al = idx / 576, rem = idx % 576, k = rem >> 6, w = rem & 63;
            int a = (cq - 2) * 2 + al;
            int sy = y - (k / 3 - 1) * 6;
            att_s[al][k][w] = (sy >= 0 && sy < 64)
                ? att[((size_t)(a * 9 + k) * N_IMG + n) * HW + sy * 64 + w] : 0.f;
        }
        __syncthreads();
    }

    if (cq < 2) {
        int cbase = cq * 128 + wv * 32;
        float mval = mask[n * HW + y * 64 + x];
        const float* fp = feats + ((size_t)(n * C_CH + cbase)) * HW + y * 64 + x;
#pragma unroll
        for (int i8 = 0; i8 < 4; i8++) {
            short8 pk;
#pragma unroll
            for (int i = 0; i < 8; i++)
                pk[i] = (short)f2bf(fp[(size_t)(i8 * 8 + i) * HW] * mval);
            *(short8*)&sx2[x][wv * 32 + i8 * 8] = pk;
        }
    } else {
        int sxo[9]; bool sxv[9]; int axk[9];
#pragma unroll
        for (int k = 0; k < 9; k++) {
            int sy = y - (k / 3 - 1) * 6, sx = x - (k % 3 - 1) * 6;
            sxo[k] = sy * 64 + sx;
            sxv[k] = (sy >= 0 && sy < 64 && sx >= 0 && sx < 64);
            axk[k] = sx;
        }
        int al = wv >> 1;             // head within this quarter's pair
        int cd = (cq - 2) * 128 + wv * 32;   // diffusion channel 0..255
        const float* vp0 = feats + ((size_t)(n * C_CH + cd)) * HW;
#pragma unroll
        for (int i8 = 0; i8 < 4; i8++) {
            short8 pk;
#pragma unroll
            for (int i = 0; i < 8; i++) {
                const float* vp = vp0 + (size_t)(i8 * 8 + i) * HW;
                float v = 0.f;
#pragma unroll
                for (int k = 0; k < 9; k++)
                    if (sxv[k]) v += vp[sxo[k]] * att_s[al][k][axk[k]];
                pk[i] = (short)f2bf(v);
            }
            *(short8*)&sx2[x][wv * 32 + i8 * 8] = pk;
        }
    }
    __syncthreads();
    // write out: 64 px x 128 ch = 1024 short8 chunks, 4 per thread
#pragma unroll
    for (int i = 0; i < 4; i++) {
        int idx = t + 256 * i;
        int px = idx >> 4, j = idx & 15;
        short8 v = *(const short8*)&sx2[px][j * 8];
        *(short8*)(xinp + ((size_t)((n * 66 + y + 1) * 66 + px + 1)) * 512
                   + cq * 128 + j * 8) = v;
    }
}

// prep: conv_w [256][512][3][3] f32 -> wt3[icc(16)][tap(9)][lq(4)][oc(256)][8] bf16
// (COALESCED A layout: lanes l15 read 16 consecutive 16B fragments per load)
__global__ __launch_bounds__(256) void k_prep_w(const float* __restrict__ cw,
                                                ushort* __restrict__ wt3) {
    int idx = blockIdx.x * 256 + threadIdx.x;   // oc*512+ic
    int oc = idx >> 9, ic = idx & 511;
    const float* p = cw + (size_t)idx * 9;
    int icc = ic >> 5, lq = (ic & 31) >> 3, pos = ic & 7;
#pragma unroll
    for (int kk = 0; kk < 9; kk++)
        wt3[((((size_t)(icc * 9 + kk)) * 4 + lq) * 256 + oc) * 8 + pos] = f2bf(p[kk]);
}

// ---------------------------------------------------------------------------
// MFMA implicit-GEMM conv (proven round-12): in-block split-K (512 threads,
// two 4-wave halves on icc 0-7 / 8-15, LDS acc-reduce epilogue) + chunk-XOR
// swizzled LDS + coalesced A layout + XCD-aware block swizzle.
#define LDS_PXW 32   // ushorts per px row (64B = 4 chunks; swizzle, no pad)
__global__ __launch_bounds__(512, 4) void k_conv_mfma(
    const ushort* __restrict__ xinp,  // [4][66][66][512] bf16, border-zeroed
    const ushort* __restrict__ wt3,   // [16][9][4][256][8] bf16 coalesced
    const float* __restrict__ cb,
    float* __restrict__ out) {
    int t512 = threadIdx.x;
    int half = t512 >> 8;             // 0: iccs 0..7, 1: iccs 8..15
    int th   = t512 & 255;            // thread id within half
    int lane = t512 & 63;
    int wid  = (t512 >> 6) & 3;       // wave within half
    int bid = blockIdx.x;
    int w   = (bid & 7) * 64 + (bid >> 3);
    int och = w & 1;
    int y0  = (w >> 1) & 63;
    int n   = w >> 7;
    int ocw = och * 128 + wid * 32;
    int l15 = lane & 15, lq = lane >> 4;

    // chunk layout: chunk = (r*4 + j)*66 + px, 16B per chunk; 792 chunks/buf
    __shared__ ushort lds[2][2][792 * 8];   // [half][buf] 50,688 B total

    f32x4 acc[2][4];
#pragma unroll
    for (int m = 0; m < 2; m++)
#pragma unroll
        for (int xs = 0; xs < 4; xs++) acc[m][xs] = (f32x4){0.f, 0.f, 0.f, 0.f};

    int s0 = th, s1 = th + 256, s2 = th + 512, s3 = th + 768;
    short8 g0, g1, g2, g3;
    int icb = half * 8;

#define SWZ_OFF(R, PX, J) (((((((R) * 66 + (PX)) << 2) | (J)) ^ ((PX) & 7)) << 3))

#define STAGE_LOAD(ICC)                                                              \
    {                                                                                \
        int icc_ = (ICC);                                                            \
        { int r = s0 / 264, rem = s0 % 264, px = rem >> 2, j = rem & 3;              \
          g0 = *(const short8*)(xinp + ((size_t)((n * 66 + y0 + r) * 66 + px)) * 512 \
                                 + icc_ * 32 + j * 8); }                             \
        { int r = s1 / 264, rem = s1 % 264, px = rem >> 2, j = rem & 3;              \
          g1 = *(const short8*)(xinp + ((size_t)((n * 66 + y0 + r) * 66 + px)) * 512 \
                                 + icc_ * 32 + j * 8); }                             \
        { int r = s2 / 264, rem = s2 % 264, px = rem >> 2, j = rem & 3;              \
          g2 = *(const short8*)(xinp + ((size_t)((n * 66 + y0 + r) * 66 + px)) * 512 \
                                 + icc_ * 32 + j * 8); }                             \
        if (s3 < 792) {                                                              \
          int r = s3 / 264, rem = s3 % 264, px = rem >> 2, j = rem & 3;              \
          g3 = *(const short8*)(xinp + ((size_t)((n * 66 + y0 + r) * 66 + px)) * 512 \
                                 + icc_ * 32 + j * 8); }                             \
    }

#define STAGE_WRITE(BUF)                                                             \
    {                                                                                \
        ushort* lb = &lds[half][BUF][0];                                             \
        { int r = s0 / 264, rem = s0 % 264, px = rem >> 2, j = rem & 3;              \
          *(short8*)&lb[SWZ_OFF(r, px, j)] = g0; }                                   \
        { int r = s1 / 264, rem = s1 % 264, px = rem >> 2, j = rem & 3;              \
          *(short8*)&lb[SWZ_OFF(r, px, j)] = g1; }                                   \
        { int r = s2 / 264, rem = s2 % 264, px = rem >> 2, j = rem & 3;              \
          *(short8*)&lb[SWZ_OFF(r, px, j)] = g2; }                                   \
        if (s3 < 792) {                                                              \
          int r = s3 / 264, rem = s3 % 264, px = rem >> 2, j = rem & 3;              \
          *(short8*)&lb[SWZ_OFF(r, px, j)] = g3; }                                   \
    }

    STAGE_LOAD(icb);
    STAGE_WRITE(0);
    __syncthreads();

    int cur = 0;
    for (int it = 0; it < 8; it++) {
        int icc = icb + it;
        if (it < 7) STAGE_LOAD(icc + 1);
        const ushort* lp = &lds[half][cur][0];
        const ushort* am0 = wt3 + (size_t)icc * 73728 + lq * 2048 + (ocw + l15) * 8;
        const ushort* am1 = am0 + 128;   // +16 oc
        short8 a0c = *(const short8*)(am0);
        short8 a1c = *(const short8*)(am1);
        short8 a0n = *(const short8*)(am0 + 8192);
        short8 a1n = *(const short8*)(am1 + 8192);
#pragma unroll
        for (int kk = 0; kk < 9; kk++) {
            short8 a0nn, a1nn;
            if (kk < 7) {
                a0nn = *(const short8*)(am0 + (kk + 2) * 8192);
                a1nn = *(const short8*)(am1 + (kk + 2) * 8192);
            }
            int ky = kk / 3, kx = kk % 3;
            int kxl = kx + l15;
            const ushort* lrow = lp + SWZ_OFF(ky, kxl, lq);
            short8 b0 = *(const short8*)(lrow);
            short8 b1 = *(const short8*)(lrow + 16 * LDS_PXW);
            short8 b2 = *(const short8*)(lrow + 32 * LDS_PXW);
            short8 b3 = *(const short8*)(lrow + 48 * LDS_PXW);
            acc[0][0] = __builtin_amdgcn_mfma_f32_16x16x32_bf16(a0c, b0, acc[0][0], 0, 0, 0);
            acc[1][0] = __builtin_amdgcn_mfma_f32_16x16x32_bf16(a1c, b0, acc[1][0], 0, 0, 0);
            acc[0][1] = __builtin_amdgcn_mfma_f32_16x16x32_bf16(a0c, b1, acc[0][1], 0, 0, 0);
            acc[1][1] = __builtin_amdgcn_mfma_f32_16x16x32_bf16(a1c, b1, acc[1][1], 0, 0, 0);
            acc[0][2] = __builtin_amdgcn_mfma_f32_16x16x32_bf16(a0c, b2, acc[0][2], 0, 0, 0);
            acc[1][2] = __builtin_amdgcn_mfma_f32_16x16x32_bf16(a1c, b2, acc[1][2], 0, 0, 0);
            acc[0][3] = __builtin_amdgcn_mfma_f32_16x16x32_bf16(a0c, b3, acc[0][3], 0, 0, 0);
            acc[1][3] = __builtin_amdgcn_mfma_f32_16x16x32_bf16(a1c, b3, acc[1][3], 0, 0, 0);
            a0c = a0n; a1c = a1n; a0n = a0nn; a1n = a1nn;
        }
        if (it < 7) {
            STAGE_WRITE(cur ^ 1);
            __syncthreads();
            cur ^= 1;
        }
    }

    float* red = (float*)&lds[0][0][0];   // 32 * 256 * 4B = 32,768 B
    __syncthreads();
    if (half == 1) {
#pragma unroll
        for (int m = 0; m < 2; m++)
#pragma unroll
            for (int xs = 0; xs < 4; xs++)
#pragma unroll
                for (int r = 0; r < 4; r++)
                    red[(((m * 4 + xs) * 4) + r) * 256 + th] = acc[m][xs][r];
    }
    __syncthreads();
    if (half == 0) {
#pragma unroll
        for (int m = 0; m < 2; m++) {
#pragma unroll
            for (int r = 0; r < 4; r++) {
                int oc = ocw + m * 16 + lq * 4 + r;
                float bias = cb[oc];
                float* op = out + ((size_t)(n * 256 + oc)) * HW + y0 * 64 + l15;
#pragma unroll
                for (int xs = 0; xs < 4; xs++)
                    op[xs * 16] = acc[m][xs][r] + red[(((m * 4 + xs) * 4) + r) * 256 + th] + bias;
            }
        }
    }
#undef STAGE_LOAD
#undef STAGE_WRITE
#undef SWZ_OFF
}

// ---------------------------------------------------------------------------
extern "C" void kernel_launch(void* const* d_in, const int* in_sizes, int n_in,
                              void* d_out, int out_size, void* d_ws, size_t ws_size,
                              hipStream_t stream) {
    const float* feats  = (const float*)d_in[0];
    const float* Kten   = (const float*)d_in[1];
    const float* Qten   = (const float*)d_in[2];
    const float* w_gap  = (const float*)d_in[3];
    const float* w_gapr = (const float*)d_in[4];
    const float* conv_w = (const float*)d_in[5];
    const float* conv_b = (const float*)d_in[6];
    const int*   label  = (const int*)d_in[7];
    float* ob           = (float*)d_out;

    float* ws = (float*)d_ws;
    float*    mask    = ws;                         // 16384
    unsigned* mmax    = (unsigned*)(ws + 16384);    // 4
    float*    S_f     = ws + 16384 + 4;             // 1024
    float*    S_r     = S_f + 1024;                 // 1024
    float*    att_inf = S_r + 1024;                 // 25*4*16384 = 1,638,400
    float*    Wpl     = att_inf + 1638400;          // 4*4*4096 = 65,536
    float*    att_dif = Wpl + 65536;                // 589,824
    ushort*   xinp    = (ushort*)(att_dif + 589824); // 8,921,088 ushorts
    ushort*   wt3     = xinp + 8921088;              // 1,179,648 ushorts

    const int NXT = N_IMG * C_CH * HW;              // 4,194,304

    // only the halo border needs zeroing; interior rewritten by k_prep_fused
    k_zero_border<<<N_IMG * 260, 256, 0, stream>>>(xinp);

    k_init<<<1, 64, 0, stream>>>(mmax);
    k_mask_m<<<N_IMG * H_DIM, 256, 0, stream>>>(feats, w_gap, label, mask, mmax);
    k_mask_norm<<<64, 256, 0, stream>>>(mask, mmax);

    k_plane_sum<<<N_IMG * C_CH, 256, 0, stream>>>(feats, S_f);
    k_pred<<<1, 128, 0, stream>>>(S_f, w_gap, ob + NXT);

    // infusion(feats, Q, K): scores -> scatter W -> weighted plane sum (GAP swap)
    k_att_inf<<<N_IMG * H_DIM, 1024, 0, stream>>>(Qten, Kten, att_inf);
    k_scatter_w<<<N_IMG * H_DIM, 256, 0, stream>>>(att_inf, Wpl);
    k_wsum<<<N_IMG * C_CH, 256, 0, stream>>>(feats, Wpl, S_r);
    k_pred<<<1, 128, 0, stream>>>(S_r, w_gapr, ob + NXT + N_IMG * NCLASS);

    // diffusion(feats, K, Q): patches from K, center from Q
    k_att_dif<<<N_IMG * H_DIM, 1024, 0, stream>>>(Kten, Qten, mask, att_dif);

    k_prep_w<<<512, 256, 0, stream>>>(conv_w, wt3);
    k_prep_fused<<<dim3(64, 4, 4), 256, 0, stream>>>(feats, mask, att_dif, xinp);

    k_conv_mfma<<<512, 512, 0, stream>>>(xinp, wt3, conv_b, ob);
}

// Round 6
// 202.882 us; speedup vs baseline: 1.1965x; 1.1965x over previous
//
#include <hip/hip_runtime.h>
#include <hip/hip_bf16.h>

#define N_IMG 4
#define C_CH 256
#define H_DIM 64
#define W_DIM 64
#define HW 4096
#define NCLASS 20
#define NHEADS 4
#define HD 64   // channels per head

typedef __attribute__((ext_vector_type(8))) short short8;
typedef __attribute__((ext_vector_type(4))) float f32x4;

__device__ __forceinline__ ushort f2bf(float f) {
    unsigned u = __float_as_uint(f);
    u += 0x7FFFu + ((u >> 16) & 1u);   // RNE
    return (ushort)(u >> 16);
}

// ---------------------------------------------------------------------------
__global__ void k_init(unsigned* mmax) {
    if (threadIdx.x < N_IMG) mmax[threadIdx.x] = 0u;
}

// mask pre-normalization + per-image max; 256 threads: 4 c-chunks x 64 w
__global__ __launch_bounds__(256) void k_mask_m(const float* __restrict__ feats,
                         const float* __restrict__ wgap,
                         const int* __restrict__ label,
                         float* __restrict__ mask, unsigned* __restrict__ mmax) {
    int b = blockIdx.x;            // N*H = 256
    int n = b >> 6, h = b & 63;
    int t = threadIdx.x;
    int w = t & 63, cq = t >> 6;
    __shared__ float wrow[C_CH];
    __shared__ float part[4][64];
    int lab = label[n];
    wrow[t] = wgap[lab * C_CH + t];
    __syncthreads();
    const float* fp = feats + ((size_t)(n * C_CH + cq * 64)) * HW + h * W_DIM + w;
    float acc = 0.f;
    for (int c = 0; c < 64; c++) acc += fp[(size_t)c * HW] * wrow[cq * 64 + c];
    part[cq][w] = acc;
    __syncthreads();
    if (cq == 0) {
        float m = fmaxf(part[0][w] + part[1][w] + part[2][w] + part[3][w], 0.f);
        mask[n * HW + h * W_DIM + w] = m;
        for (int off = 32; off; off >>= 1) m = fmaxf(m, __shfl_down(m, off, 64));
        if (w == 0) atomicMax(&mmax[n], __float_as_uint(m));
    }
}

__global__ void k_mask_norm(float* __restrict__ mask, const unsigned* __restrict__ mmax) {
    int i = blockIdx.x * 256 + threadIdx.x;
    if (i < N_IMG * HW) {
        int n = i / HW;
        float mx = fmaxf(__uint_as_float(mmax[n]), 1.0f);
        mask[i] = mask[i] / mx;
    }
}

// per-(n,c) plane sum for GAP on feats
__global__ void k_plane_sum(const float* __restrict__ x, float* __restrict__ S) {
    int nc = blockIdx.x;
    const float* p = x + (size_t)nc * HW;
    float s = 0.f;
    for (int i = threadIdx.x; i < HW; i += 256) s += p[i];
    __shared__ float red[4];
    for (int off = 32; off; off >>= 1) s += __shfl_down(s, off, 64);
    int wid = threadIdx.x >> 6;
    if ((threadIdx.x & 63) == 0) red[wid] = s;
    __syncthreads();
    if (threadIdx.x == 0) S[nc] = red[0] + red[1] + red[2] + red[3];
}

__global__ void k_pred(const float* __restrict__ S, const float* __restrict__ wg,
                       float* __restrict__ out) {
    int idx = threadIdx.x;
    if (idx < N_IMG * NCLASS) {
        int n = idx / NCLASS, k = idx % NCLASS;
        float s = 0.f;
        for (int c = 0; c < C_CH; c++) s += wg[k * C_CH + c] * S[n * C_CH + c];
        out[idx] = s * (1.0f / HW);
    }
}

// ---------------------------------------------------------------------------
// infusion attention scores (5x5, dil 3): 16-wave structure, writes normalized
// att to global. att[((a*25+k)*N + n)*HW + h*64 + w]
__global__ __launch_bounds__(1024) void k_att_inf(
    const float* __restrict__ patch_t,   // Q (im2col side)
    const float* __restrict__ center_t,  // K (center side)
    float* __restrict__ att) {
    int b = blockIdx.x;                 // N*H = 256
    int n = b >> 6, h = b & 63;
    int t = threadIdx.x;
    int w = t & 63;
    int a = (t >> 6) & 3;
    int cq = t >> 8;                    // channel quarter
    __shared__ float att_s[4][25][64];  // 25.6 KB
    for (int i = t; i < 4 * 25 * 64; i += 1024) ((float*)att_s)[i] = 0.f;
    __syncthreads();

    int off[25];
#pragma unroll
    for (int k = 0; k < 25; k++) {
        int y = h + (k / 5 - 2) * 3, x = w + (k % 5 - 2) * 3;
        off[k] = (y >= 0 && y < 64 && x >= 0 && x < 64) ? y * 64 + x : -1;
    }
    float s[25];
#pragma unroll
    for (int k = 0; k < 25; k++) s[k] = 0.f;
    const float* cp = center_t + ((size_t)(n * C_CH + a * HD + cq * 16)) * HW + h * W_DIM + w;
    const float* pp = patch_t + ((size_t)(n * C_CH + a * HD + cq * 16)) * HW;
    for (int c = 0; c < 16; c++) {
        float cen = cp[(size_t)c * HW];
        const float* pc = pp + (size_t)c * HW;
#pragma unroll
        for (int k = 0; k < 25; k++) {
            float pv = (off[k] >= 0) ? pc[off[k]] : 0.f;
            s[k] += pv * cen;
        }
    }
#pragma unroll
    for (int k = 0; k < 25; k++) atomicAdd(&att_s[a][k][w], s[k]);
    __syncthreads();
    if (cq == 0) {
        float v[25];
        float mx = -1e30f;
#pragma unroll
        for (int k = 0; k < 25; k++) { v[k] = att_s[a][k][w]; mx = fmaxf(mx, v[k]); }
        float sum = 0.f;
#pragma unroll
        for (int k = 0; k < 25; k++) { v[k] = __expf(v[k] - mx); sum += v[k]; }
        float inv = 1.0f / sum;
#pragma unroll
        for (int k = 0; k < 25; k++)
            att[((size_t)(a * 25 + k) * N_IMG + n) * HW + h * 64 + w] = v[k] * inv;
    }
}

// W_a[n,y,x] = sum_k att[a,k,(y-dy_k, x-dx_k)] (scatter form of the GAP sum)
__global__ __launch_bounds__(256) void k_scatter_w(const float* __restrict__ att,
                                                   float* __restrict__ W) {
    int b = blockIdx.x;   // n*64 + y
    int n = b >> 6, y = b & 63;
    int t = threadIdx.x;
    int x = t & 63, a = t >> 6;
    float s = 0.f;
#pragma unroll
    for (int k = 0; k < 25; k++) {
        int sy = y - (k / 5 - 2) * 3, sx = x - (k % 5 - 2) * 3;
        if (sy >= 0 && sy < 64 && sx >= 0 && sx < 64)
            s += att[((size_t)(a * 25 + k) * N_IMG + n) * HW + sy * 64 + sx];
    }
    W[((size_t)a * N_IMG + n) * HW + y * 64 + x] = s;
}

// S_r[n,c] = sum_px feats[n,c,px] * W[a(c),n,px]  (weighted plane sum, f32x4)
__global__ __launch_bounds__(256) void k_wsum(const float* __restrict__ V,
                                              const float* __restrict__ W,
                                              float* __restrict__ S) {
    int nc = blockIdx.x;               // n*256 + c
    int n = nc >> 8, c = nc & 255;
    int a = c >> 6;
    const f32x4* p4 = (const f32x4*)(V + (size_t)nc * HW);
    const f32x4* w4 = (const f32x4*)(W + ((size_t)a * N_IMG + n) * HW);
    f32x4 a4 = (f32x4){0.f, 0.f, 0.f, 0.f};
    for (int i = threadIdx.x; i < HW / 4; i += 256) {
        f32x4 u = p4[i], v = w4[i];
        a4 += u * v;
    }
    float s = a4[0] + a4[1] + a4[2] + a4[3];
    __shared__ float red[4];
    for (int off = 32; off; off >>= 1) s += __shfl_down(s, off, 64);
    int wid = threadIdx.x >> 6;
    if ((threadIdx.x & 63) == 0) red[wid] = s;
    __syncthreads();
    if (threadIdx.x == 0) S[nc] = red[0] + red[1] + red[2] + red[3];
}

// ---------------------------------------------------------------------------
// diffusion attention scores (3x3, dil 6), masked — 16-wave version
__global__ __launch_bounds__(1024) void k_att_dif(
    const float* __restrict__ patch_t,   // K
    const float* __restrict__ center_t,  // Q
    const float* __restrict__ mask, float* __restrict__ att) {
    int b = blockIdx.x;                 // N*H = 256
    int n = b >> 6, h = b & 63;
    int t = threadIdx.x;
    int w = t & 63;
    int a = (t >> 6) & 3;
    int cq = t >> 8;
    __shared__ float att_s[4][9][64];   // 9.2 KB
    for (int i = t; i < 4 * 9 * 64; i += 1024) ((float*)att_s)[i] = 0.f;
    __syncthreads();

    int off[9];
#pragma unroll
    for (int k = 0; k < 9; k++) {
        int y = h + (k / 3 - 1) * 6, x = w + (k % 3 - 1) * 6;
        off[k] = (y >= 0 && y < 64 && x >= 0 && x < 64) ? y * 64 + x : -1;
    }
    float s[9];
#pragma unroll
    for (int k = 0; k < 9; k++) s[k] = 0.f;
    const float* cp = center_t + ((size_t)(n * C_CH + a * HD + cq * 16)) * HW + h * W_DIM + w;
    const float* pp = patch_t + ((size_t)(n * C_CH + a * HD + cq * 16)) * HW;
    for (int c = 0; c < 16; c++) {
        float cen = cp[(size_t)c * HW];
        const float* pc = pp + (size_t)c * HW;
#pragma unroll
        for (int k = 0; k < 9; k++) {
            float pv = (off[k] >= 0) ? pc[off[k]] : 0.f;
            s[k] += pv * cen;
        }
    }
#pragma unroll
    for (int k = 0; k < 9; k++) atomicAdd(&att_s[a][k][w], s[k]);
    __syncthreads();
    if (cq == 0) {
        float v[9];
        float mx = -1e30f;
#pragma unroll
        for (int k = 0; k < 9; k++) { v[k] = att_s[a][k][w]; mx = fmaxf(mx, v[k]); }
        float sum = 0.f;
#pragma unroll
        for (int k = 0; k < 9; k++) { v[k] = __expf(v[k] - mx); sum += v[k]; }
        float mm = mask[n * HW + h * W_DIM + w] / sum;
#pragma unroll
        for (int k = 0; k < 9; k++)
            att[((size_t)(a * 9 + k) * N_IMG + n) * HW + h * W_DIM + w] = v[k] * mm;
    }
}

// ---------------------------------------------------------------------------
// Zero only the halo border of xinp [4][66][66][512] (interior is fully
// rewritten by k_prep_fused every launch). 260 segments of 512 ushorts per n.
__global__ __launch_bounds__(256) void k_zero_border(ushort* __restrict__ xinp) {
    int b = blockIdx.x;            // n*260 + seg
    int n = b / 260, seg = b % 260;
    size_t base;
    if (seg < 66)       base = ((size_t)(n * 66 + 0) * 66 + seg) * 512;
    else if (seg < 132) base = ((size_t)(n * 66 + 65) * 66 + (seg - 66)) * 512;
    else {
        int c = seg - 132;
        int r = 1 + (c >> 1), x = (c & 1) ? 65 : 0;
        base = ((size_t)(n * 66 + r) * 66 + x) * 512;
    }
    ((unsigned*)(xinp + base))[threadIdx.x] = 0u;   // 256 x 4B = 1024B = 512 ushorts
}

// ---------------------------------------------------------------------------
// FUSED conv-input prep, round-14: latency-model fix. Grid (64 y, 4 n, 16 g),
// 32 channels per block. g<8: feats*mask (8 independent plane loads/thread).
// g>=8: diffusion — batch-stage 3 feats rows (y-6,y,y+6) x 32ch x 64px into
// a 24KB LDS tile with 24 independent coalesced wave-loads (deep MLP), att
// rows in LDS, then compute entirely from LDS. Both paths write via a small
// padded LDS transpose -> 64B-chunk coalesced global writes.
__global__ __launch_bounds__(256) void k_prep_fused(
    const float* __restrict__ feats, const float* __restrict__ mask,
    const float* __restrict__ att, ushort* __restrict__ xinp) {
    int y = blockIdx.x, n = blockIdx.y, g = blockIdx.z;   // g 0..15
    int t = threadIdx.x;
    int x = t & 63, cg = t >> 6;       // 4 waves x 8 channels
    __shared__ float ftile[3][32][64];  // 24.0 KB
    __shared__ float att_s[9][64];      //  2.3 KB
    __shared__ ushort sx[64][36];       //  4.5 KB (pad 36: ~conflict-free)
    short8 pk;
    if (g < 8) {
        int cbase = g * 32 + cg * 8;
        float mval = mask[n * HW + y * 64 + x];
        const float* fp = feats + ((size_t)(n * C_CH + cbase)) * HW + y * 64 + x;
        float v[8];
#pragma unroll
        for (int i = 0; i < 8; i++) v[i] = fp[(size_t)i * HW];
#pragma unroll
        for (int i = 0; i < 8; i++) pk[i] = (short)f2bf(v[i] * mval);
    } else {
        int gd = g - 8;
        int a = gd >> 1;
        int cd = gd * 32;              // diffusion channel base (0..255)
        for (int idx = t; idx < 9 * 64; idx += 256) {
            int k = idx >> 6, w = idx & 63;
            int sy = y - (k / 3 - 1) * 6;
            att_s[k][w] = (sy >= 0 && sy < 64)
                ? att[((size_t)(a * 9 + k) * N_IMG + n) * HW + sy * 64 + w] : 0.f;
        }
        const float* fb = feats + ((size_t)(n * C_CH + cd)) * HW;
#pragma unroll
        for (int i = 0; i < 24; i++) {
            int idx = t + 256 * i;
            int r = idx >> 11, c = (idx >> 6) & 31, xx = idx & 63;
            int ry = y + (r - 1) * 6;
            ((float*)ftile)[idx] = (ry >= 0 && ry < 64)
                ? fb[(size_t)c * HW + ry * 64 + xx] : 0.f;
        }
        __syncthreads();
#pragma unroll
        for (int cl = 0; cl < 8; cl++) {
            int c = cg * 8 + cl;
            float v = 0.f;
#pragma unroll
            for (int k = 0; k < 9; k++) {
                int sxk = x - (k % 3 - 1) * 6;
                if (sxk >= 0 && sxk < 64)
                    v += ftile[2 - k / 3][c][sxk] * att_s[k][sxk];
            }
            pk[cl] = (short)f2bf(v);
        }
    }
    __syncthreads();
    *(short8*)&sx[x][cg * 8] = pk;
    __syncthreads();
    int px = t >> 2, j = t & 3;
    short8 v8 = *(const short8*)&sx[px][j * 8];
    int chb = (g < 8) ? g * 32 : 256 + (g - 8) * 32;
    *(short8*)(xinp + ((size_t)((n * 66 + y + 1) * 66 + px + 1)) * 512 + chb + j * 8) = v8;
}

// prep: conv_w [256][512][3][3] f32 -> wt3[icc(16)][tap(9)][lq(4)][oc(256)][8] bf16
// (COALESCED A layout: lanes l15 read 16 consecutive 16B fragments per load)
__global__ __launch_bounds__(256) void k_prep_w(const float* __restrict__ cw,
                                                ushort* __restrict__ wt3) {
    int idx = blockIdx.x * 256 + threadIdx.x;   // oc*512+ic
    int oc = idx >> 9, ic = idx & 511;
    const float* p = cw + (size_t)idx * 9;
    int icc = ic >> 5, lq = (ic & 31) >> 3, pos = ic & 7;
#pragma unroll
    for (int kk = 0; kk < 9; kk++)
        wt3[((((size_t)(icc * 9 + kk)) * 4 + lq) * 256 + oc) * 8 + pos] = f2bf(p[kk]);
}

// ---------------------------------------------------------------------------
// MFMA implicit-GEMM conv (proven round-12): in-block split-K (512 threads,
// two 4-wave halves on icc 0-7 / 8-15, LDS acc-reduce epilogue) + chunk-XOR
// swizzled LDS + coalesced A layout + XCD-aware block swizzle.
#define LDS_PXW 32   // ushorts per px row (64B = 4 chunks; swizzle, no pad)
__global__ __launch_bounds__(512, 4) void k_conv_mfma(
    const ushort* __restrict__ xinp,  // [4][66][66][512] bf16, border-zeroed
    const ushort* __restrict__ wt3,   // [16][9][4][256][8] bf16 coalesced
    const float* __restrict__ cb,
    float* __restrict__ out) {
    int t512 = threadIdx.x;
    int half = t512 >> 8;             // 0: iccs 0..7, 1: iccs 8..15
    int th   = t512 & 255;            // thread id within half
    int lane = t512 & 63;
    int wid  = (t512 >> 6) & 3;       // wave within half
    int bid = blockIdx.x;
    int w   = (bid & 7) * 64 + (bid >> 3);
    int och = w & 1;
    int y0  = (w >> 1) & 63;
    int n   = w >> 7;
    int ocw = och * 128 + wid * 32;
    int l15 = lane & 15, lq = lane >> 4;

    // chunk layout: chunk = (r*4 + j)*66 + px, 16B per chunk; 792 chunks/buf
    __shared__ ushort lds[2][2][792 * 8];   // [half][buf] 50,688 B total

    f32x4 acc[2][4];
#pragma unroll
    for (int m = 0; m < 2; m++)
#pragma unroll
        for (int xs = 0; xs < 4; xs++) acc[m][xs] = (f32x4){0.f, 0.f, 0.f, 0.f};

    int s0 = th, s1 = th + 256, s2 = th + 512, s3 = th + 768;
    short8 g0, g1, g2, g3;
    int icb = half * 8;

#define SWZ_OFF(R, PX, J) (((((((R) * 66 + (PX)) << 2) | (J)) ^ ((PX) & 7)) << 3))

#define STAGE_LOAD(ICC)                                                              \
    {                                                                                \
        int icc_ = (ICC);                                                            \
        { int r = s0 / 264, rem = s0 % 264, px = rem >> 2, j = rem & 3;              \
          g0 = *(const short8*)(xinp + ((size_t)((n * 66 + y0 + r) * 66 + px)) * 512 \
                                 + icc_ * 32 + j * 8); }                             \
        { int r = s1 / 264, rem = s1 % 264, px = rem >> 2, j = rem & 3;              \
          g1 = *(const short8*)(xinp + ((size_t)((n * 66 + y0 + r) * 66 + px)) * 512 \
                                 + icc_ * 32 + j * 8); }                             \
        { int r = s2 / 264, rem = s2 % 264, px = rem >> 2, j = rem & 3;              \
          g2 = *(const short8*)(xinp + ((size_t)((n * 66 + y0 + r) * 66 + px)) * 512 \
                                 + icc_ * 32 + j * 8); }                             \
        if (s3 < 792) {                                                              \
          int r = s3 / 264, rem = s3 % 264, px = rem >> 2, j = rem & 3;              \
          g3 = *(const short8*)(xinp + ((size_t)((n * 66 + y0 + r) * 66 + px)) * 512 \
                                 + icc_ * 32 + j * 8); }                             \
    }

#define STAGE_WRITE(BUF)                                                             \
    {                                                                                \
        ushort* lb = &lds[half][BUF][0];                                             \
        { int r = s0 / 264, rem = s0 % 264, px = rem >> 2, j = rem & 3;              \
          *(short8*)&lb[SWZ_OFF(r, px, j)] = g0; }                                   \
        { int r = s1 / 264, rem = s1 % 264, px = rem >> 2, j = rem & 3;              \
          *(short8*)&lb[SWZ_OFF(r, px, j)] = g1; }                                   \
        { int r = s2 / 264, rem = s2 % 264, px = rem >> 2, j = rem & 3;              \
          *(short8*)&lb[SWZ_OFF(r, px, j)] = g2; }                                   \
        if (s3 < 792) {                                                              \
          int r = s3 / 264, rem = s3 % 264, px = rem >> 2, j = rem & 3;              \
          *(short8*)&lb[SWZ_OFF(r, px, j)] = g3; }                                   \
    }

    STAGE_LOAD(icb);
    STAGE_WRITE(0);
    __syncthreads();

    int cur = 0;
    for (int it = 0; it < 8; it++) {
        int icc = icb + it;
        if (it < 7) STAGE_LOAD(icc + 1);
        const ushort* lp = &lds[half][cur][0];
        const ushort* am0 = wt3 + (size_t)icc * 73728 + lq * 2048 + (ocw + l15) * 8;
        const ushort* am1 = am0 + 128;   // +16 oc
        short8 a0c = *(const short8*)(am0);
        short8 a1c = *(const short8*)(am1);
        short8 a0n = *(const short8*)(am0 + 8192);
        short8 a1n = *(const short8*)(am1 + 8192);
#pragma unroll
        for (int kk = 0; kk < 9; kk++) {
            short8 a0nn, a1nn;
            if (kk < 7) {
                a0nn = *(const short8*)(am0 + (kk + 2) * 8192);
                a1nn = *(const short8*)(am1 + (kk + 2) * 8192);
            }
            int ky = kk / 3, kx = kk % 3;
            int kxl = kx + l15;
            const ushort* lrow = lp + SWZ_OFF(ky, kxl, lq);
            short8 b0 = *(const short8*)(lrow);
            short8 b1 = *(const short8*)(lrow + 16 * LDS_PXW);
            short8 b2 = *(const short8*)(lrow + 32 * LDS_PXW);
            short8 b3 = *(const short8*)(lrow + 48 * LDS_PXW);
            acc[0][0] = __builtin_amdgcn_mfma_f32_16x16x32_bf16(a0c, b0, acc[0][0], 0, 0, 0);
            acc[1][0] = __builtin_amdgcn_mfma_f32_16x16x32_bf16(a1c, b0, acc[1][0], 0, 0, 0);
            acc[0][1] = __builtin_amdgcn_mfma_f32_16x16x32_bf16(a0c, b1, acc[0][1], 0, 0, 0);
            acc[1][1] = __builtin_amdgcn_mfma_f32_16x16x32_bf16(a1c, b1, acc[1][1], 0, 0, 0);
            acc[0][2] = __builtin_amdgcn_mfma_f32_16x16x32_bf16(a0c, b2, acc[0][2], 0, 0, 0);
            acc[1][2] = __builtin_amdgcn_mfma_f32_16x16x32_bf16(a1c, b2, acc[1][2], 0, 0, 0);
            acc[0][3] = __builtin_amdgcn_mfma_f32_16x16x32_bf16(a0c, b3, acc[0][3], 0, 0, 0);
            acc[1][3] = __builtin_amdgcn_mfma_f32_16x16x32_bf16(a1c, b3, acc[1][3], 0, 0, 0);
            a0c = a0n; a1c = a1n; a0n = a0nn; a1n = a1nn;
        }
        if (it < 7) {
            STAGE_WRITE(cur ^ 1);
            __syncthreads();
            cur ^= 1;
        }
    }

    float* red = (float*)&lds[0][0][0];   // 32 * 256 * 4B = 32,768 B
    __syncthreads();
    if (half == 1) {
#pragma unroll
        for (int m = 0; m < 2; m++)
#pragma unroll
            for (int xs = 0; xs < 4; xs++)
#pragma unroll
                for (int r = 0; r < 4; r++)
                    red[(((m * 4 + xs) * 4) + r) * 256 + th] = acc[m][xs][r];
    }
    __syncthreads();
    if (half == 0) {
#pragma unroll
        for (int m = 0; m < 2; m++) {
#pragma unroll
            for (int r = 0; r < 4; r++) {
                int oc = ocw + m * 16 + lq * 4 + r;
                float bias = cb[oc];
                float* op = out + ((size_t)(n * 256 + oc)) * HW + y0 * 64 + l15;
#pragma unroll
                for (int xs = 0; xs < 4; xs++)
                    op[xs * 16] = acc[m][xs][r] + red[(((m * 4 + xs) * 4) + r) * 256 + th] + bias;
            }
        }
    }
#undef STAGE_LOAD
#undef STAGE_WRITE
#undef SWZ_OFF
}

// ---------------------------------------------------------------------------
extern "C" void kernel_launch(void* const* d_in, const int* in_sizes, int n_in,
                              void* d_out, int out_size, void* d_ws, size_t ws_size,
                              hipStream_t stream) {
    const float* feats  = (const float*)d_in[0];
    const float* Kten   = (const float*)d_in[1];
    const float* Qten   = (const float*)d_in[2];
    const float* w_gap  = (const float*)d_in[3];
    const float* w_gapr = (const float*)d_in[4];
    const float* conv_w = (const float*)d_in[5];
    const float* conv_b = (const float*)d_in[6];
    const int*   label  = (const int*)d_in[7];
    float* ob           = (float*)d_out;

    float* ws = (float*)d_ws;
    float*    mask    = ws;                         // 16384
    unsigned* mmax    = (unsigned*)(ws + 16384);    // 4
    float*    S_f     = ws + 16384 + 4;             // 1024
    float*    S_r     = S_f + 1024;                 // 1024
    float*    att_inf = S_r + 1024;                 // 25*4*16384 = 1,638,400
    float*    Wpl     = att_inf + 1638400;          // 4*4*4096 = 65,536
    float*    att_dif = Wpl + 65536;                // 589,824
    ushort*   xinp    = (ushort*)(att_dif + 589824); // 8,921,088 ushorts
    ushort*   wt3     = xinp + 8921088;              // 1,179,648 ushorts

    const int NXT = N_IMG * C_CH * HW;              // 4,194,304

    // only the halo border needs zeroing; interior rewritten by k_prep_fused
    k_zero_border<<<N_IMG * 260, 256, 0, stream>>>(xinp);

    k_init<<<1, 64, 0, stream>>>(mmax);
    k_mask_m<<<N_IMG * H_DIM, 256, 0, stream>>>(feats, w_gap, label, mask, mmax);
    k_mask_norm<<<64, 256, 0, stream>>>(mask, mmax);

    k_plane_sum<<<N_IMG * C_CH, 256, 0, stream>>>(feats, S_f);
    k_pred<<<1, 128, 0, stream>>>(S_f, w_gap, ob + NXT);

    // infusion(feats, Q, K): scores -> scatter W -> weighted plane sum (GAP swap)
    k_att_inf<<<N_IMG * H_DIM, 1024, 0, stream>>>(Qten, Kten, att_inf);
    k_scatter_w<<<N_IMG * H_DIM, 256, 0, stream>>>(att_inf, Wpl);
    k_wsum<<<N_IMG * C_CH, 256, 0, stream>>>(feats, Wpl, S_r);
    k_pred<<<1, 128, 0, stream>>>(S_r, w_gapr, ob + NXT + N_IMG * NCLASS);

    // diffusion(feats, K, Q): patches from K, center from Q
    k_att_dif<<<N_IMG * H_DIM, 1024, 0, stream>>>(Kten, Qten, mask, att_dif);

    k_prep_w<<<512, 256, 0, stream>>>(conv_w, wt3);
    k_prep_fused<<<dim3(64, 4, 16), 256, 0, stream>>>(feats, mask, att_dif, xinp);

    k_conv_mfma<<<512, 512, 0, stream>>>(xinp, wt3, conv_b, ob);
}

// Round 7
// 199.192 us; speedup vs baseline: 1.2186x; 1.0185x over previous
//
#include <hip/hip_runtime.h>
#include <hip/hip_bf16.h>

#define N_IMG 4
#define C_CH 256
#define H_DIM 64
#define W_DIM 64
#define HW 4096
#define NCLASS 20
#define NHEADS 4
#define HD 64   // channels per head

typedef __attribute__((ext_vector_type(8))) short short8;
typedef __attribute__((ext_vector_type(4))) float f32x4;

__device__ __forceinline__ ushort f2bf(float f) {
    unsigned u = __float_as_uint(f);
    u += 0x7FFFu + ((u >> 16) & 1u);   // RNE
    return (ushort)(u >> 16);
}

// ---------------------------------------------------------------------------
__global__ void k_init(unsigned* mmax) {
    if (threadIdx.x < N_IMG) mmax[threadIdx.x] = 0u;
}

// mask pre-normalization + per-image max; 256 threads: 4 c-chunks x 64 w
__global__ __launch_bounds__(256) void k_mask_m(const float* __restrict__ feats,
                         const float* __restrict__ wgap,
                         const int* __restrict__ label,
                         float* __restrict__ mask, unsigned* __restrict__ mmax) {
    int b = blockIdx.x;            // N*H = 256
    int n = b >> 6, h = b & 63;
    int t = threadIdx.x;
    int w = t & 63, cq = t >> 6;
    __shared__ float wrow[C_CH];
    __shared__ float part[4][64];
    int lab = label[n];
    wrow[t] = wgap[lab * C_CH + t];
    __syncthreads();
    const float* fp = feats + ((size_t)(n * C_CH + cq * 64)) * HW + h * W_DIM + w;
    float acc = 0.f;
    for (int c = 0; c < 64; c++) acc += fp[(size_t)c * HW] * wrow[cq * 64 + c];
    part[cq][w] = acc;
    __syncthreads();
    if (cq == 0) {
        float m = fmaxf(part[0][w] + part[1][w] + part[2][w] + part[3][w], 0.f);
        mask[n * HW + h * W_DIM + w] = m;
        for (int off = 32; off; off >>= 1) m = fmaxf(m, __shfl_down(m, off, 64));
        if (w == 0) atomicMax(&mmax[n], __float_as_uint(m));
    }
}

__global__ void k_mask_norm(float* __restrict__ mask, const unsigned* __restrict__ mmax) {
    int i = blockIdx.x * 256 + threadIdx.x;
    if (i < N_IMG * HW) {
        int n = i / HW;
        float mx = fmaxf(__uint_as_float(mmax[n]), 1.0f);
        mask[i] = mask[i] / mx;
    }
}

// per-(n,c) plane sum for GAP on feats
__global__ void k_plane_sum(const float* __restrict__ x, float* __restrict__ S) {
    int nc = blockIdx.x;
    const float* p = x + (size_t)nc * HW;
    float s = 0.f;
    for (int i = threadIdx.x; i < HW; i += 256) s += p[i];
    __shared__ float red[4];
    for (int off = 32; off; off >>= 1) s += __shfl_down(s, off, 64);
    int wid = threadIdx.x >> 6;
    if ((threadIdx.x & 63) == 0) red[wid] = s;
    __syncthreads();
    if (threadIdx.x == 0) S[nc] = red[0] + red[1] + red[2] + red[3];
}

__global__ void k_pred(const float* __restrict__ S, const float* __restrict__ wg,
                       float* __restrict__ out) {
    int idx = threadIdx.x;
    if (idx < N_IMG * NCLASS) {
        int n = idx / NCLASS, k = idx % NCLASS;
        float s = 0.f;
        for (int c = 0; c < C_CH; c++) s += wg[k * C_CH + c] * S[n * C_CH + c];
        out[idx] = s * (1.0f / HW);
    }
}

// ---------------------------------------------------------------------------
// infusion attention scores (5x5, dil 3), round-15: TAP-SPLIT layout.
// 1024 thr = (w 64, a 4, kq 4); each thread owns 6-7 taps x ALL 64 channels
// of its head -> s[7]+off[7] live regs (vs 50), deep load pipeline, and
// exclusive att_s writes (no LDS atomics). Softmax tail unchanged.
__global__ __launch_bounds__(1024) void k_att_inf(
    const float* __restrict__ patch_t,   // Q (im2col side)
    const float* __restrict__ center_t,  // K (center side)
    float* __restrict__ att) {
    int b = blockIdx.x;                 // N*H = 256
    int n = b >> 6, h = b & 63;
    int t = threadIdx.x;
    int w = t & 63;
    int a = (t >> 6) & 3;
    int kq = t >> 8;                    // tap quarter
    __shared__ float att_s[4][25][64];  // 25.6 KB

    int k0 = (kq == 0) ? 0 : (1 + kq * 6);   // 0,7,13,19
    int nk = (kq == 0) ? 7 : 6;

    int off[7];
#pragma unroll
    for (int j = 0; j < 7; j++) {
        int k = k0 + ((j < nk) ? j : 0);
        int y = h + (k / 5 - 2) * 3, x = w + (k % 5 - 2) * 3;
        off[j] = (y >= 0 && y < 64 && x >= 0 && x < 64) ? y * 64 + x : -1;
    }
    float s[7];
#pragma unroll
    for (int j = 0; j < 7; j++) s[j] = 0.f;

    const float* cp = center_t + ((size_t)(n * C_CH + a * HD)) * HW + h * W_DIM + w;
    const float* pp = patch_t + ((size_t)(n * C_CH + a * HD)) * HW;
    for (int c = 0; c < 64; c++) {
        float cen = cp[(size_t)c * HW];
        const float* pc = pp + (size_t)c * HW;
#pragma unroll
        for (int j = 0; j < 7; j++) {
            if (j < nk) {
                float pv = (off[j] >= 0) ? pc[off[j]] : 0.f;
                s[j] += pv * cen;
            }
        }
    }
#pragma unroll
    for (int j = 0; j < 7; j++)
        if (j < nk) att_s[a][k0 + j][w] = s[j];
    __syncthreads();

    if (t < 256) {
        int ww = t & 63, aa = t >> 6;
        float v[25];
        float mx = -1e30f;
#pragma unroll
        for (int k = 0; k < 25; k++) { v[k] = att_s[aa][k][ww]; mx = fmaxf(mx, v[k]); }
        float sum = 0.f;
#pragma unroll
        for (int k = 0; k < 25; k++) { v[k] = __expf(v[k] - mx); sum += v[k]; }
        float inv = 1.0f / sum;
#pragma unroll
        for (int k = 0; k < 25; k++)
            att[((size_t)(aa * 25 + k) * N_IMG + n) * HW + h * 64 + ww] = v[k] * inv;
    }
}

// W_a[n,y,x] = sum_k att[a,k,(y-dy_k, x-dx_k)] (scatter form of the GAP sum)
__global__ __launch_bounds__(256) void k_scatter_w(const float* __restrict__ att,
                                                   float* __restrict__ W) {
    int b = blockIdx.x;   // n*64 + y
    int n = b >> 6, y = b & 63;
    int t = threadIdx.x;
    int x = t & 63, a = t >> 6;
    float s = 0.f;
#pragma unroll
    for (int k = 0; k < 25; k++) {
        int sy = y - (k / 5 - 2) * 3, sx = x - (k % 5 - 2) * 3;
        if (sy >= 0 && sy < 64 && sx >= 0 && sx < 64)
            s += att[((size_t)(a * 25 + k) * N_IMG + n) * HW + sy * 64 + sx];
    }
    W[((size_t)a * N_IMG + n) * HW + y * 64 + x] = s;
}

// S_r[n,c] = sum_px feats[n,c,px] * W[a(c),n,px]  (weighted plane sum, f32x4)
__global__ __launch_bounds__(256) void k_wsum(const float* __restrict__ V,
                                              const float* __restrict__ W,
                                              float* __restrict__ S) {
    int nc = blockIdx.x;               // n*256 + c
    int n = nc >> 8, c = nc & 255;
    int a = c >> 6;
    const f32x4* p4 = (const f32x4*)(V + (size_t)nc * HW);
    const f32x4* w4 = (const f32x4*)(W + ((size_t)a * N_IMG + n) * HW);
    f32x4 a4 = (f32x4){0.f, 0.f, 0.f, 0.f};
    for (int i = threadIdx.x; i < HW / 4; i += 256) {
        f32x4 u = p4[i], v = w4[i];
        a4 += u * v;
    }
    float s = a4[0] + a4[1] + a4[2] + a4[3];
    __shared__ float red[4];
    for (int off = 32; off; off >>= 1) s += __shfl_down(s, off, 64);
    int wid = threadIdx.x >> 6;
    if ((threadIdx.x & 63) == 0) red[wid] = s;
    __syncthreads();
    if (threadIdx.x == 0) S[nc] = red[0] + red[1] + red[2] + red[3];
}

// ---------------------------------------------------------------------------
// diffusion attention scores (3x3, dil 6), masked — 16-wave version
__global__ __launch_bounds__(1024) void k_att_dif(
    const float* __restrict__ patch_t,   // K
    const float* __restrict__ center_t,  // Q
    const float* __restrict__ mask, float* __restrict__ att) {
    int b = blockIdx.x;                 // N*H = 256
    int n = b >> 6, h = b & 63;
    int t = threadIdx.x;
    int w = t & 63;
    int a = (t >> 6) & 3;
    int cq = t >> 8;
    __shared__ float att_s[4][9][64];   // 9.2 KB
    for (int i = t; i < 4 * 9 * 64; i += 1024) ((float*)att_s)[i] = 0.f;
    __syncthreads();

    int off[9];
#pragma unroll
    for (int k = 0; k < 9; k++) {
        int y = h + (k / 3 - 1) * 6, x = w + (k % 3 - 1) * 6;
        off[k] = (y >= 0 && y < 64 && x >= 0 && x < 64) ? y * 64 + x : -1;
    }
    float s[9];
#pragma unroll
    for (int k = 0; k < 9; k++) s[k] = 0.f;
    const float* cp = center_t + ((size_t)(n * C_CH + a * HD + cq * 16)) * HW + h * W_DIM + w;
    const float* pp = patch_t + ((size_t)(n * C_CH + a * HD + cq * 16)) * HW;
    for (int c = 0; c < 16; c++) {
        float cen = cp[(size_t)c * HW];
        const float* pc = pp + (size_t)c * HW;
#pragma unroll
        for (int k = 0; k < 9; k++) {
            float pv = (off[k] >= 0) ? pc[off[k]] : 0.f;
            s[k] += pv * cen;
        }
    }
#pragma unroll
    for (int k = 0; k < 9; k++) atomicAdd(&att_s[a][k][w], s[k]);
    __syncthreads();
    if (cq == 0) {
        float v[9];
        float mx = -1e30f;
#pragma unroll
        for (int k = 0; k < 9; k++) { v[k] = att_s[a][k][w]; mx = fmaxf(mx, v[k]); }
        float sum = 0.f;
#pragma unroll
        for (int k = 0; k < 9; k++) { v[k] = __expf(v[k] - mx); sum += v[k]; }
        float mm = mask[n * HW + h * W_DIM + w] / sum;
#pragma unroll
        for (int k = 0; k < 9; k++)
            att[((size_t)(a * 9 + k) * N_IMG + n) * HW + h * W_DIM + w] = v[k] * mm;
    }
}

// ---------------------------------------------------------------------------
// Zero only the halo border of xinp [4][66][66][512] (interior is fully
// rewritten by k_prep_fused every launch). 260 segments of 512 ushorts per n.
__global__ __launch_bounds__(256) void k_zero_border(ushort* __restrict__ xinp) {
    int b = blockIdx.x;            // n*260 + seg
    int n = b / 260, seg = b % 260;
    size_t base;
    if (seg < 66)       base = ((size_t)(n * 66 + 0) * 66 + seg) * 512;
    else if (seg < 132) base = ((size_t)(n * 66 + 65) * 66 + (seg - 66)) * 512;
    else {
        int c = seg - 132;
        int r = 1 + (c >> 1), x = (c & 1) ? 65 : 0;
        base = ((size_t)(n * 66 + r) * 66 + x) * 512;
    }
    ((unsigned*)(xinp + base))[threadIdx.x] = 0u;   // 256 x 4B = 1024B = 512 ushorts
}

// ---------------------------------------------------------------------------
// FUSED conv-input prep (proven round-14): Grid (64 y, 4 n, 16 g), 32 ch/block.
// g<8: feats*mask; g>=8: diffusion via 24KB LDS row tile. Coalesced writes.
__global__ __launch_bounds__(256) void k_prep_fused(
    const float* __restrict__ feats, const float* __restrict__ mask,
    const float* __restrict__ att, ushort* __restrict__ xinp) {
    int y = blockIdx.x, n = blockIdx.y, g = blockIdx.z;   // g 0..15
    int t = threadIdx.x;
    int x = t & 63, cg = t >> 6;       // 4 waves x 8 channels
    __shared__ float ftile[3][32][64];  // 24.0 KB
    __shared__ float att_s[9][64];      //  2.3 KB
    __shared__ ushort sx[64][36];       //  4.5 KB (pad 36: ~conflict-free)
    short8 pk;
    if (g < 8) {
        int cbase = g * 32 + cg * 8;
        float mval = mask[n * HW + y * 64 + x];
        const float* fp = feats + ((size_t)(n * C_CH + cbase)) * HW + y * 64 + x;
        float v[8];
#pragma unroll
        for (int i = 0; i < 8; i++) v[i] = fp[(size_t)i * HW];
#pragma unroll
        for (int i = 0; i < 8; i++) pk[i] = (short)f2bf(v[i] * mval);
    } else {
        int gd = g - 8;
        int a = gd >> 1;
        int cd = gd * 32;              // diffusion channel base (0..255)
        for (int idx = t; idx < 9 * 64; idx += 256) {
            int k = idx >> 6, w = idx & 63;
            int sy = y - (k / 3 - 1) * 6;
            att_s[k][w] = (sy >= 0 && sy < 64)
                ? att[((size_t)(a * 9 + k) * N_IMG + n) * HW + sy * 64 + w] : 0.f;
        }
        const float* fb = feats + ((size_t)(n * C_CH + cd)) * HW;
#pragma unroll
        for (int i = 0; i < 24; i++) {
            int idx = t + 256 * i;
            int r = idx >> 11, c = (idx >> 6) & 31, xx = idx & 63;
            int ry = y + (r - 1) * 6;
            ((float*)ftile)[idx] = (ry >= 0 && ry < 64)
                ? fb[(size_t)c * HW + ry * 64 + xx] : 0.f;
        }
        __syncthreads();
#pragma unroll
        for (int cl = 0; cl < 8; cl++) {
            int c = cg * 8 + cl;
            float v = 0.f;
#pragma unroll
            for (int k = 0; k < 9; k++) {
                int sxk = x - (k % 3 - 1) * 6;
                if (sxk >= 0 && sxk < 64)
                    v += ftile[2 - k / 3][c][sxk] * att_s[k][sxk];
            }
            pk[cl] = (short)f2bf(v);
        }
    }
    __syncthreads();
    *(short8*)&sx[x][cg * 8] = pk;
    __syncthreads();
    int px = t >> 2, j = t & 3;
    short8 v8 = *(const short8*)&sx[px][j * 8];
    int chb = (g < 8) ? g * 32 : 256 + (g - 8) * 32;
    *(short8*)(xinp + ((size_t)((n * 66 + y + 1) * 66 + px + 1)) * 512 + chb + j * 8) = v8;
}

// prep: conv_w [256][512][3][3] f32 -> wt3[icc(16)][tap(9)][lq(4)][oc(256)][8] bf16
// (COALESCED A layout: lanes l15 read 16 consecutive 16B fragments per load)
__global__ __launch_bounds__(256) void k_prep_w(const float* __restrict__ cw,
                                                ushort* __restrict__ wt3) {
    int idx = blockIdx.x * 256 + threadIdx.x;   // oc*512+ic
    int oc = idx >> 9, ic = idx & 511;
    const float* p = cw + (size_t)idx * 9;
    int icc = ic >> 5, lq = (ic & 31) >> 3, pos = ic & 7;
#pragma unroll
    for (int kk = 0; kk < 9; kk++)
        wt3[((((size_t)(icc * 9 + kk)) * 4 + lq) * 256 + oc) * 8 + pos] = f2bf(p[kk]);
}

// ---------------------------------------------------------------------------
// MFMA implicit-GEMM conv (proven round-12): in-block split-K (512 threads,
// two 4-wave halves on icc 0-7 / 8-15, LDS acc-reduce epilogue) + chunk-XOR
// swizzled LDS + coalesced A layout + XCD-aware block swizzle.
#define LDS_PXW 32   // ushorts per px row (64B = 4 chunks; swizzle, no pad)
__global__ __launch_bounds__(512, 4) void k_conv_mfma(
    const ushort* __restrict__ xinp,  // [4][66][66][512] bf16, border-zeroed
    const ushort* __restrict__ wt3,   // [16][9][4][256][8] bf16 coalesced
    const float* __restrict__ cb,
    float* __restrict__ out) {
    int t512 = threadIdx.x;
    int half = t512 >> 8;             // 0: iccs 0..7, 1: iccs 8..15
    int th   = t512 & 255;            // thread id within half
    int lane = t512 & 63;
    int wid  = (t512 >> 6) & 3;       // wave within half
    int bid = blockIdx.x;
    int w   = (bid & 7) * 64 + (bid >> 3);
    int och = w & 1;
    int y0  = (w >> 1) & 63;
    int n   = w >> 7;
    int ocw = och * 128 + wid * 32;
    int l15 = lane & 15, lq = lane >> 4;

    // chunk layout: chunk = (r*4 + j)*66 + px, 16B per chunk; 792 chunks/buf
    __shared__ ushort lds[2][2][792 * 8];   // [half][buf] 50,688 B total

    f32x4 acc[2][4];
#pragma unroll
    for (int m = 0; m < 2; m++)
#pragma unroll
        for (int xs = 0; xs < 4; xs++) acc[m][xs] = (f32x4){0.f, 0.f, 0.f, 0.f};

    int s0 = th, s1 = th + 256, s2 = th + 512, s3 = th + 768;
    short8 g0, g1, g2, g3;
    int icb = half * 8;

#define SWZ_OFF(R, PX, J) (((((((R) * 66 + (PX)) << 2) | (J)) ^ ((PX) & 7)) << 3))

#define STAGE_LOAD(ICC)                                                              \
    {                                                                                \
        int icc_ = (ICC);                                                            \
        { int r = s0 / 264, rem = s0 % 264, px = rem >> 2, j = rem & 3;              \
          g0 = *(const short8*)(xinp + ((size_t)((n * 66 + y0 + r) * 66 + px)) * 512 \
                                 + icc_ * 32 + j * 8); }                             \
        { int r = s1 / 264, rem = s1 % 264, px = rem >> 2, j = rem & 3;              \
          g1 = *(const short8*)(xinp + ((size_t)((n * 66 + y0 + r) * 66 + px)) * 512 \
                                 + icc_ * 32 + j * 8); }                             \
        { int r = s2 / 264, rem = s2 % 264, px = rem >> 2, j = rem & 3;              \
          g2 = *(const short8*)(xinp + ((size_t)((n * 66 + y0 + r) * 66 + px)) * 512 \
                                 + icc_ * 32 + j * 8); }                             \
        if (s3 < 792) {                                                              \
          int r = s3 / 264, rem = s3 % 264, px = rem >> 2, j = rem & 3;              \
          g3 = *(const short8*)(xinp + ((size_t)((n * 66 + y0 + r) * 66 + px)) * 512 \
                                 + icc_ * 32 + j * 8); }                             \
    }

#define STAGE_WRITE(BUF)                                                             \
    {                                                                                \
        ushort* lb = &lds[half][BUF][0];                                             \
        { int r = s0 / 264, rem = s0 % 264, px = rem >> 2, j = rem & 3;              \
          *(short8*)&lb[SWZ_OFF(r, px, j)] = g0; }                                   \
        { int r = s1 / 264, rem = s1 % 264, px = rem >> 2, j = rem & 3;              \
          *(short8*)&lb[SWZ_OFF(r, px, j)] = g1; }                                   \
        { int r = s2 / 264, rem = s2 % 264, px = rem >> 2, j = rem & 3;              \
          *(short8*)&lb[SWZ_OFF(r, px, j)] = g2; }                                   \
        if (s3 < 792) {                                                              \
          int r = s3 / 264, rem = s3 % 264, px = rem >> 2, j = rem & 3;              \
          *(short8*)&lb[SWZ_OFF(r, px, j)] = g3; }                                   \
    }

    STAGE_LOAD(icb);
    STAGE_WRITE(0);
    __syncthreads();

    int cur = 0;
    for (int it = 0; it < 8; it++) {
        int icc = icb + it;
        if (it < 7) STAGE_LOAD(icc + 1);
        const ushort* lp = &lds[half][cur][0];
        const ushort* am0 = wt3 + (size_t)icc * 73728 + lq * 2048 + (ocw + l15) * 8;
        const ushort* am1 = am0 + 128;   // +16 oc
        short8 a0c = *(const short8*)(am0);
        short8 a1c = *(const short8*)(am1);
        short8 a0n = *(const short8*)(am0 + 8192);
        short8 a1n = *(const short8*)(am1 + 8192);
#pragma unroll
        for (int kk = 0; kk < 9; kk++) {
            short8 a0nn, a1nn;
            if (kk < 7) {
                a0nn = *(const short8*)(am0 + (kk + 2) * 8192);
                a1nn = *(const short8*)(am1 + (kk + 2) * 8192);
            }
            int ky = kk / 3, kx = kk % 3;
            int kxl = kx + l15;
            const ushort* lrow = lp + SWZ_OFF(ky, kxl, lq);
            short8 b0 = *(const short8*)(lrow);
            short8 b1 = *(const short8*)(lrow + 16 * LDS_PXW);
            short8 b2 = *(const short8*)(lrow + 32 * LDS_PXW);
            short8 b3 = *(const short8*)(lrow + 48 * LDS_PXW);
            acc[0][0] = __builtin_amdgcn_mfma_f32_16x16x32_bf16(a0c, b0, acc[0][0], 0, 0, 0);
            acc[1][0] = __builtin_amdgcn_mfma_f32_16x16x32_bf16(a1c, b0, acc[1][0], 0, 0, 0);
            acc[0][1] = __builtin_amdgcn_mfma_f32_16x16x32_bf16(a0c, b1, acc[0][1], 0, 0, 0);
            acc[1][1] = __builtin_amdgcn_mfma_f32_16x16x32_bf16(a1c, b1, acc[1][1], 0, 0, 0);
            acc[0][2] = __builtin_amdgcn_mfma_f32_16x16x32_bf16(a0c, b2, acc[0][2], 0, 0, 0);
            acc[1][2] = __builtin_amdgcn_mfma_f32_16x16x32_bf16(a1c, b2, acc[1][2], 0, 0, 0);
            acc[0][3] = __builtin_amdgcn_mfma_f32_16x16x32_bf16(a0c, b3, acc[0][3], 0, 0, 0);
            acc[1][3] = __builtin_amdgcn_mfma_f32_16x16x32_bf16(a1c, b3, acc[1][3], 0, 0, 0);
            a0c = a0n; a1c = a1n; a0n = a0nn; a1n = a1nn;
        }
        if (it < 7) {
            STAGE_WRITE(cur ^ 1);
            __syncthreads();
            cur ^= 1;
        }
    }

    float* red = (float*)&lds[0][0][0];   // 32 * 256 * 4B = 32,768 B
    __syncthreads();
    if (half == 1) {
#pragma unroll
        for (int m = 0; m < 2; m++)
#pragma unroll
            for (int xs = 0; xs < 4; xs++)
#pragma unroll
                for (int r = 0; r < 4; r++)
                    red[(((m * 4 + xs) * 4) + r) * 256 + th] = acc[m][xs][r];
    }
    __syncthreads();
    if (half == 0) {
#pragma unroll
        for (int m = 0; m < 2; m++) {
#pragma unroll
            for (int r = 0; r < 4; r++) {
                int oc = ocw + m * 16 + lq * 4 + r;
                float bias = cb[oc];
                float* op = out + ((size_t)(n * 256 + oc)) * HW + y0 * 64 + l15;
#pragma unroll
                for (int xs = 0; xs < 4; xs++)
                    op[xs * 16] = acc[m][xs][r] + red[(((m * 4 + xs) * 4) + r) * 256 + th] + bias;
            }
        }
    }
#undef STAGE_LOAD
#undef STAGE_WRITE
#undef SWZ_OFF
}

// ---------------------------------------------------------------------------
extern "C" void kernel_launch(void* const* d_in, const int* in_sizes, int n_in,
                              void* d_out, int out_size, void* d_ws, size_t ws_size,
                              hipStream_t stream) {
    const float* feats  = (const float*)d_in[0];
    const float* Kten   = (const float*)d_in[1];
    const float* Qten   = (const float*)d_in[2];
    const float* w_gap  = (const float*)d_in[3];
    const float* w_gapr = (const float*)d_in[4];
    const float* conv_w = (const float*)d_in[5];
    const float* conv_b = (const float*)d_in[6];
    const int*   label  = (const int*)d_in[7];
    float* ob           = (float*)d_out;

    float* ws = (float*)d_ws;
    float*    mask    = ws;                         // 16384
    unsigned* mmax    = (unsigned*)(ws + 16384);    // 4
    float*    S_f     = ws + 16384 + 4;             // 1024
    float*    S_r     = S_f + 1024;                 // 1024
    float*    att_inf = S_r + 1024;                 // 25*4*16384 = 1,638,400
    float*    Wpl     = att_inf + 1638400;          // 4*4*4096 = 65,536
    float*    att_dif = Wpl + 65536;                // 589,824
    ushort*   xinp    = (ushort*)(att_dif + 589824); // 8,921,088 ushorts
    ushort*   wt3     = xinp + 8921088;              // 1,179,648 ushorts

    const int NXT = N_IMG * C_CH * HW;              // 4,194,304

    // only the halo border needs zeroing; interior rewritten by k_prep_fused
    k_zero_border<<<N_IMG * 260, 256, 0, stream>>>(xinp);

    k_init<<<1, 64, 0, stream>>>(mmax);
    k_mask_m<<<N_IMG * H_DIM, 256, 0, stream>>>(feats, w_gap, label, mask, mmax);
    k_mask_norm<<<64, 256, 0, stream>>>(mask, mmax);

    k_plane_sum<<<N_IMG * C_CH, 256, 0, stream>>>(feats, S_f);
    k_pred<<<1, 128, 0, stream>>>(S_f, w_gap, ob + NXT);

    // infusion(feats, Q, K): scores -> scatter W -> weighted plane sum (GAP swap)
    k_att_inf<<<N_IMG * H_DIM, 1024, 0, stream>>>(Qten, Kten, att_inf);
    k_scatter_w<<<N_IMG * H_DIM, 256, 0, stream>>>(att_inf, Wpl);
    k_wsum<<<N_IMG * C_CH, 256, 0, stream>>>(feats, Wpl, S_r);
    k_pred<<<1, 128, 0, stream>>>(S_r, w_gapr, ob + NXT + N_IMG * NCLASS);

    // diffusion(feats, K, Q): patches from K, center from Q
    k_att_dif<<<N_IMG * H_DIM, 1024, 0, stream>>>(Kten, Qten, mask, att_dif);

    k_prep_w<<<512, 256, 0, stream>>>(conv_w, wt3);
    k_prep_fused<<<dim3(64, 4, 16), 256, 0, stream>>>(feats, mask, att_dif, xinp);

    k_conv_mfma<<<512, 512, 0, stream>>>(xinp, wt3, conv_b, ob);
}

// Round 8
// 180.740 us; speedup vs baseline: 1.3431x; 1.1021x over previous
//
#include <hip/hip_runtime.h>
#include <hip/hip_bf16.h>

#define N_IMG 4
#define C_CH 256
#define H_DIM 64
#define W_DIM 64
#define HW 4096
#define NCLASS 20
#define NHEADS 4
#define HD 64   // channels per head

typedef __attribute__((ext_vector_type(8))) short short8;
typedef __attribute__((ext_vector_type(4))) float f32x4;

__device__ __forceinline__ ushort f2bf(float f) {
    unsigned u = __float_as_uint(f);
    u += 0x7FFFu + ((u >> 16) & 1u);   // RNE
    return (ushort)(u >> 16);
}

// ---------------------------------------------------------------------------
__global__ void k_init(unsigned* mmax) {
    if (threadIdx.x < N_IMG) mmax[threadIdx.x] = 0u;
}

// mask pre-normalization + per-image max; 256 threads: 4 c-chunks x 64 w
__global__ __launch_bounds__(256) void k_mask_m(const float* __restrict__ feats,
                         const float* __restrict__ wgap,
                         const int* __restrict__ label,
                         float* __restrict__ mask, unsigned* __restrict__ mmax) {
    int b = blockIdx.x;            // N*H = 256
    int n = b >> 6, h = b & 63;
    int t = threadIdx.x;
    int w = t & 63, cq = t >> 6;
    __shared__ float wrow[C_CH];
    __shared__ float part[4][64];
    int lab = label[n];
    wrow[t] = wgap[lab * C_CH + t];
    __syncthreads();
    const float* fp = feats + ((size_t)(n * C_CH + cq * 64)) * HW + h * W_DIM + w;
    float acc = 0.f;
    for (int c = 0; c < 64; c++) acc += fp[(size_t)c * HW] * wrow[cq * 64 + c];
    part[cq][w] = acc;
    __syncthreads();
    if (cq == 0) {
        float m = fmaxf(part[0][w] + part[1][w] + part[2][w] + part[3][w], 0.f);
        mask[n * HW + h * W_DIM + w] = m;
        for (int off = 32; off; off >>= 1) m = fmaxf(m, __shfl_down(m, off, 64));
        if (w == 0) atomicMax(&mmax[n], __float_as_uint(m));
    }
}

__global__ void k_mask_norm(float* __restrict__ mask, const unsigned* __restrict__ mmax) {
    int i = blockIdx.x * 256 + threadIdx.x;
    if (i < N_IMG * HW) {
        int n = i / HW;
        float mx = fmaxf(__uint_as_float(mmax[n]), 1.0f);
        mask[i] = mask[i] / mx;
    }
}

// per-(n,c) plane sum for GAP on feats
__global__ void k_plane_sum(const float* __restrict__ x, float* __restrict__ S) {
    int nc = blockIdx.x;
    const float* p = x + (size_t)nc * HW;
    float s = 0.f;
    for (int i = threadIdx.x; i < HW; i += 256) s += p[i];
    __shared__ float red[4];
    for (int off = 32; off; off >>= 1) s += __shfl_down(s, off, 64);
    int wid = threadIdx.x >> 6;
    if ((threadIdx.x & 63) == 0) red[wid] = s;
    __syncthreads();
    if (threadIdx.x == 0) S[nc] = red[0] + red[1] + red[2] + red[3];
}

__global__ void k_pred(const float* __restrict__ S, const float* __restrict__ wg,
                       float* __restrict__ out) {
    int idx = threadIdx.x;
    if (idx < N_IMG * NCLASS) {
        int n = idx / NCLASS, k = idx % NCLASS;
        float s = 0.f;
        for (int c = 0; c < C_CH; c++) s += wg[k * C_CH + c] * S[n * C_CH + c];
        out[idx] = s * (1.0f / HW);
    }
}

// ---------------------------------------------------------------------------
// infusion attention scores (5x5, dil 3), round-16: per-head 256-thread
// blocks (grid 256 x 4) + explicit c x4 unroll with batched register loads
// (~32 loads in flight/wave) + branchless OOB (always-load, mask-multiply).
// kq is wave-uniform so the 7th-tap guard is a scalar branch.
__global__ __launch_bounds__(256) void k_att_inf(
    const float* __restrict__ patch_t,   // Q (im2col side)
    const float* __restrict__ center_t,  // K (center side)
    float* __restrict__ att) {
    int b = blockIdx.x;                 // N*H = 256
    int n = b >> 6, h = b & 63;
    int a = blockIdx.y;                 // head
    int t = threadIdx.x;
    int w = t & 63;
    int kq = t >> 6;                    // tap quarter (wave-uniform)
    __shared__ float att_s[25][64];     // 6.4 KB

    int k0 = (kq == 0) ? 0 : (1 + kq * 6);   // 0,7,13,19
    int nk = (kq == 0) ? 7 : 6;

    int offc[7]; float msk[7];
#pragma unroll
    for (int j = 0; j < 7; j++) {
        int k = k0 + ((j < nk) ? j : 0);
        int y = h + (k / 5 - 2) * 3, x = w + (k % 5 - 2) * 3;
        bool v = (y >= 0 && y < 64 && x >= 0 && x < 64) && (j < nk);
        offc[j] = v ? y * 64 + x : 0;
        msk[j] = v ? 1.f : 0.f;
    }
    float s[7];
#pragma unroll
    for (int j = 0; j < 7; j++) s[j] = 0.f;

    const float* cp = center_t + ((size_t)(n * C_CH + a * HD)) * HW + h * W_DIM + w;
    const float* pp = patch_t + ((size_t)(n * C_CH + a * HD)) * HW;
    for (int c4 = 0; c4 < 64; c4 += 4) {
        float cen[4];
        float pv[4][7];
#pragma unroll
        for (int u = 0; u < 4; u++)
            cen[u] = cp[(size_t)(c4 + u) * HW];
#pragma unroll
        for (int u = 0; u < 4; u++) {
            const float* pc = pp + (size_t)(c4 + u) * HW;
#pragma unroll
            for (int j = 0; j < 7; j++)
                if (j < nk) pv[u][j] = pc[offc[j]];
        }
#pragma unroll
        for (int u = 0; u < 4; u++)
#pragma unroll
            for (int j = 0; j < 7; j++)
                if (j < nk) s[j] += pv[u][j] * msk[j] * cen[u];
    }
#pragma unroll
    for (int j = 0; j < 7; j++)
        if (j < nk) att_s[k0 + j][w] = s[j];
    __syncthreads();

    if (t < 64) {
        float v[25];
        float mx = -1e30f;
#pragma unroll
        for (int k = 0; k < 25; k++) { v[k] = att_s[k][t]; mx = fmaxf(mx, v[k]); }
        float sum = 0.f;
#pragma unroll
        for (int k = 0; k < 25; k++) { v[k] = __expf(v[k] - mx); sum += v[k]; }
        float inv = 1.0f / sum;
#pragma unroll
        for (int k = 0; k < 25; k++)
            att[((size_t)(a * 25 + k) * N_IMG + n) * HW + h * 64 + t] = v[k] * inv;
    }
}

// W_a[n,y,x] = sum_k att[a,k,(y-dy_k, x-dx_k)] (scatter form of the GAP sum)
__global__ __launch_bounds__(256) void k_scatter_w(const float* __restrict__ att,
                                                   float* __restrict__ W) {
    int b = blockIdx.x;   // n*64 + y
    int n = b >> 6, y = b & 63;
    int t = threadIdx.x;
    int x = t & 63, a = t >> 6;
    float s = 0.f;
#pragma unroll
    for (int k = 0; k < 25; k++) {
        int sy = y - (k / 5 - 2) * 3, sx = x - (k % 5 - 2) * 3;
        if (sy >= 0 && sy < 64 && sx >= 0 && sx < 64)
            s += att[((size_t)(a * 25 + k) * N_IMG + n) * HW + sy * 64 + sx];
    }
    W[((size_t)a * N_IMG + n) * HW + y * 64 + x] = s;
}

// S_r[n,c] = sum_px feats[n,c,px] * W[a(c),n,px]  (weighted plane sum, f32x4)
__global__ __launch_bounds__(256) void k_wsum(const float* __restrict__ V,
                                              const float* __restrict__ W,
                                              float* __restrict__ S) {
    int nc = blockIdx.x;               // n*256 + c
    int n = nc >> 8, c = nc & 255;
    int a = c >> 6;
    const f32x4* p4 = (const f32x4*)(V + (size_t)nc * HW);
    const f32x4* w4 = (const f32x4*)(W + ((size_t)a * N_IMG + n) * HW);
    f32x4 a4 = (f32x4){0.f, 0.f, 0.f, 0.f};
    for (int i = threadIdx.x; i < HW / 4; i += 256) {
        f32x4 u = p4[i], v = w4[i];
        a4 += u * v;
    }
    float s = a4[0] + a4[1] + a4[2] + a4[3];
    __shared__ float red[4];
    for (int off = 32; off; off >>= 1) s += __shfl_down(s, off, 64);
    int wid = threadIdx.x >> 6;
    if ((threadIdx.x & 63) == 0) red[wid] = s;
    __syncthreads();
    if (threadIdx.x == 0) S[nc] = red[0] + red[1] + red[2] + red[3];
}

// ---------------------------------------------------------------------------
// diffusion attention scores (3x3, dil 6), masked — 16-wave version
__global__ __launch_bounds__(1024) void k_att_dif(
    const float* __restrict__ patch_t,   // K
    const float* __restrict__ center_t,  // Q
    const float* __restrict__ mask, float* __restrict__ att) {
    int b = blockIdx.x;                 // N*H = 256
    int n = b >> 6, h = b & 63;
    int t = threadIdx.x;
    int w = t & 63;
    int a = (t >> 6) & 3;
    int cq = t >> 8;
    __shared__ float att_s[4][9][64];   // 9.2 KB
    for (int i = t; i < 4 * 9 * 64; i += 1024) ((float*)att_s)[i] = 0.f;
    __syncthreads();

    int off[9];
#pragma unroll
    for (int k = 0; k < 9; k++) {
        int y = h + (k / 3 - 1) * 6, x = w + (k % 3 - 1) * 6;
        off[k] = (y >= 0 && y < 64 && x >= 0 && x < 64) ? y * 64 + x : -1;
    }
    float s[9];
#pragma unroll
    for (int k = 0; k < 9; k++) s[k] = 0.f;
    const float* cp = center_t + ((size_t)(n * C_CH + a * HD + cq * 16)) * HW + h * W_DIM + w;
    const float* pp = patch_t + ((size_t)(n * C_CH + a * HD + cq * 16)) * HW;
    for (int c = 0; c < 16; c++) {
        float cen = cp[(size_t)c * HW];
        const float* pc = pp + (size_t)c * HW;
#pragma unroll
        for (int k = 0; k < 9; k++) {
            float pv = (off[k] >= 0) ? pc[off[k]] : 0.f;
            s[k] += pv * cen;
        }
    }
#pragma unroll
    for (int k = 0; k < 9; k++) atomicAdd(&att_s[a][k][w], s[k]);
    __syncthreads();
    if (cq == 0) {
        float v[9];
        float mx = -1e30f;
#pragma unroll
        for (int k = 0; k < 9; k++) { v[k] = att_s[a][k][w]; mx = fmaxf(mx, v[k]); }
        float sum = 0.f;
#pragma unroll
        for (int k = 0; k < 9; k++) { v[k] = __expf(v[k] - mx); sum += v[k]; }
        float mm = mask[n * HW + h * W_DIM + w] / sum;
#pragma unroll
        for (int k = 0; k < 9; k++)
            att[((size_t)(a * 9 + k) * N_IMG + n) * HW + h * W_DIM + w] = v[k] * mm;
    }
}

// ---------------------------------------------------------------------------
// Zero only the halo border of xinp [4][66][66][512] (interior is fully
// rewritten by k_prep_fused every launch). 260 segments of 512 ushorts per n.
__global__ __launch_bounds__(256) void k_zero_border(ushort* __restrict__ xinp) {
    int b = blockIdx.x;            // n*260 + seg
    int n = b / 260, seg = b % 260;
    size_t base;
    if (seg < 66)       base = ((size_t)(n * 66 + 0) * 66 + seg) * 512;
    else if (seg < 132) base = ((size_t)(n * 66 + 65) * 66 + (seg - 66)) * 512;
    else {
        int c = seg - 132;
        int r = 1 + (c >> 1), x = (c & 1) ? 65 : 0;
        base = ((size_t)(n * 66 + r) * 66 + x) * 512;
    }
    ((unsigned*)(xinp + base))[threadIdx.x] = 0u;   // 256 x 4B = 1024B = 512 ushorts
}

// ---------------------------------------------------------------------------
// FUSED conv-input prep (proven round-14): Grid (64 y, 4 n, 16 g), 32 ch/block.
// g<8: feats*mask; g>=8: diffusion via 24KB LDS row tile. Coalesced writes.
__global__ __launch_bounds__(256) void k_prep_fused(
    const float* __restrict__ feats, const float* __restrict__ mask,
    const float* __restrict__ att, ushort* __restrict__ xinp) {
    int y = blockIdx.x, n = blockIdx.y, g = blockIdx.z;   // g 0..15
    int t = threadIdx.x;
    int x = t & 63, cg = t >> 6;       // 4 waves x 8 channels
    __shared__ float ftile[3][32][64];  // 24.0 KB
    __shared__ float att_s[9][64];      //  2.3 KB
    __shared__ ushort sx[64][36];       //  4.5 KB (pad 36: ~conflict-free)
    short8 pk;
    if (g < 8) {
        int cbase = g * 32 + cg * 8;
        float mval = mask[n * HW + y * 64 + x];
        const float* fp = feats + ((size_t)(n * C_CH + cbase)) * HW + y * 64 + x;
        float v[8];
#pragma unroll
        for (int i = 0; i < 8; i++) v[i] = fp[(size_t)i * HW];
#pragma unroll
        for (int i = 0; i < 8; i++) pk[i] = (short)f2bf(v[i] * mval);
    } else {
        int gd = g - 8;
        int a = gd >> 1;
        int cd = gd * 32;              // diffusion channel base (0..255)
        for (int idx = t; idx < 9 * 64; idx += 256) {
            int k = idx >> 6, w = idx & 63;
            int sy = y - (k / 3 - 1) * 6;
            att_s[k][w] = (sy >= 0 && sy < 64)
                ? att[((size_t)(a * 9 + k) * N_IMG + n) * HW + sy * 64 + w] : 0.f;
        }
        const float* fb = feats + ((size_t)(n * C_CH + cd)) * HW;
#pragma unroll
        for (int i = 0; i < 24; i++) {
            int idx = t + 256 * i;
            int r = idx >> 11, c = (idx >> 6) & 31, xx = idx & 63;
            int ry = y + (r - 1) * 6;
            ((float*)ftile)[idx] = (ry >= 0 && ry < 64)
                ? fb[(size_t)c * HW + ry * 64 + xx] : 0.f;
        }
        __syncthreads();
#pragma unroll
        for (int cl = 0; cl < 8; cl++) {
            int c = cg * 8 + cl;
            float v = 0.f;
#pragma unroll
            for (int k = 0; k < 9; k++) {
                int sxk = x - (k % 3 - 1) * 6;
                if (sxk >= 0 && sxk < 64)
                    v += ftile[2 - k / 3][c][sxk] * att_s[k][sxk];
            }
            pk[cl] = (short)f2bf(v);
        }
    }
    __syncthreads();
    *(short8*)&sx[x][cg * 8] = pk;
    __syncthreads();
    int px = t >> 2, j = t & 3;
    short8 v8 = *(const short8*)&sx[px][j * 8];
    int chb = (g < 8) ? g * 32 : 256 + (g - 8) * 32;
    *(short8*)(xinp + ((size_t)((n * 66 + y + 1) * 66 + px + 1)) * 512 + chb + j * 8) = v8;
}

// prep: conv_w [256][512][3][3] f32 -> wt3[icc(16)][tap(9)][lq(4)][oc(256)][8] bf16
// (COALESCED A layout: lanes l15 read 16 consecutive 16B fragments per load)
__global__ __launch_bounds__(256) void k_prep_w(const float* __restrict__ cw,
                                                ushort* __restrict__ wt3) {
    int idx = blockIdx.x * 256 + threadIdx.x;   // oc*512+ic
    int oc = idx >> 9, ic = idx & 511;
    const float* p = cw + (size_t)idx * 9;
    int icc = ic >> 5, lq = (ic & 31) >> 3, pos = ic & 7;
#pragma unroll
    for (int kk = 0; kk < 9; kk++)
        wt3[((((size_t)(icc * 9 + kk)) * 4 + lq) * 256 + oc) * 8 + pos] = f2bf(p[kk]);
}

// ---------------------------------------------------------------------------
// MFMA implicit-GEMM conv (proven round-12): in-block split-K (512 threads,
// two 4-wave halves on icc 0-7 / 8-15, LDS acc-reduce epilogue) + chunk-XOR
// swizzled LDS + coalesced A layout + XCD-aware block swizzle.
#define LDS_PXW 32   // ushorts per px row (64B = 4 chunks; swizzle, no pad)
__global__ __launch_bounds__(512, 4) void k_conv_mfma(
    const ushort* __restrict__ xinp,  // [4][66][66][512] bf16, border-zeroed
    const ushort* __restrict__ wt3,   // [16][9][4][256][8] bf16 coalesced
    const float* __restrict__ cb,
    float* __restrict__ out) {
    int t512 = threadIdx.x;
    int half = t512 >> 8;             // 0: iccs 0..7, 1: iccs 8..15
    int th   = t512 & 255;            // thread id within half
    int lane = t512 & 63;
    int wid  = (t512 >> 6) & 3;       // wave within half
    int bid = blockIdx.x;
    int w   = (bid & 7) * 64 + (bid >> 3);
    int och = w & 1;
    int y0  = (w >> 1) & 63;
    int n   = w >> 7;
    int ocw = och * 128 + wid * 32;
    int l15 = lane & 15, lq = lane >> 4;

    // chunk layout: chunk = (r*4 + j)*66 + px, 16B per chunk; 792 chunks/buf
    __shared__ ushort lds[2][2][792 * 8];   // [half][buf] 50,688 B total

    f32x4 acc[2][4];
#pragma unroll
    for (int m = 0; m < 2; m++)
#pragma unroll
        for (int xs = 0; xs < 4; xs++) acc[m][xs] = (f32x4){0.f, 0.f, 0.f, 0.f};

    int s0 = th, s1 = th + 256, s2 = th + 512, s3 = th + 768;
    short8 g0, g1, g2, g3;
    int icb = half * 8;

#define SWZ_OFF(R, PX, J) (((((((R) * 66 + (PX)) << 2) | (J)) ^ ((PX) & 7)) << 3))

#define STAGE_LOAD(ICC)                                                              \
    {                                                                                \
        int icc_ = (ICC);                                                            \
        { int r = s0 / 264, rem = s0 % 264, px = rem >> 2, j = rem & 3;              \
          g0 = *(const short8*)(xinp + ((size_t)((n * 66 + y0 + r) * 66 + px)) * 512 \
                                 + icc_ * 32 + j * 8); }                             \
        { int r = s1 / 264, rem = s1 % 264, px = rem >> 2, j = rem & 3;              \
          g1 = *(const short8*)(xinp + ((size_t)((n * 66 + y0 + r) * 66 + px)) * 512 \
                                 + icc_ * 32 + j * 8); }                             \
        { int r = s2 / 264, rem = s2 % 264, px = rem >> 2, j = rem & 3;              \
          g2 = *(const short8*)(xinp + ((size_t)((n * 66 + y0 + r) * 66 + px)) * 512 \
                                 + icc_ * 32 + j * 8); }                             \
        if (s3 < 792) {                                                              \
          int r = s3 / 264, rem = s3 % 264, px = rem >> 2, j = rem & 3;              \
          g3 = *(const short8*)(xinp + ((size_t)((n * 66 + y0 + r) * 66 + px)) * 512 \
                                 + icc_ * 32 + j * 8); }                             \
    }

#define STAGE_WRITE(BUF)                                                             \
    {                                                                                \
        ushort* lb = &lds[half][BUF][0];                                             \
        { int r = s0 / 264, rem = s0 % 264, px = rem >> 2, j = rem & 3;              \
          *(short8*)&lb[SWZ_OFF(r, px, j)] = g0; }                                   \
        { int r = s1 / 264, rem = s1 % 264, px = rem >> 2, j = rem & 3;              \
          *(short8*)&lb[SWZ_OFF(r, px, j)] = g1; }                                   \
        { int r = s2 / 264, rem = s2 % 264, px = rem >> 2, j = rem & 3;              \
          *(short8*)&lb[SWZ_OFF(r, px, j)] = g2; }                                   \
        if (s3 < 792) {                                                              \
          int r = s3 / 264, rem = s3 % 264, px = rem >> 2, j = rem & 3;              \
          *(short8*)&lb[SWZ_OFF(r, px, j)] = g3; }                                   \
    }

    STAGE_LOAD(icb);
    STAGE_WRITE(0);
    __syncthreads();

    int cur = 0;
    for (int it = 0; it < 8; it++) {
        int icc = icb + it;
        if (it < 7) STAGE_LOAD(icc + 1);
        const ushort* lp = &lds[half][cur][0];
        const ushort* am0 = wt3 + (size_t)icc * 73728 + lq * 2048 + (ocw + l15) * 8;
        const ushort* am1 = am0 + 128;   // +16 oc
        short8 a0c = *(const short8*)(am0);
        short8 a1c = *(const short8*)(am1);
        short8 a0n = *(const short8*)(am0 + 8192);
        short8 a1n = *(const short8*)(am1 + 8192);
#pragma unroll
        for (int kk = 0; kk < 9; kk++) {
            short8 a0nn, a1nn;
            if (kk < 7) {
                a0nn = *(const short8*)(am0 + (kk + 2) * 8192);
                a1nn = *(const short8*)(am1 + (kk + 2) * 8192);
            }
            int ky = kk / 3, kx = kk % 3;
            int kxl = kx + l15;
            const ushort* lrow = lp + SWZ_OFF(ky, kxl, lq);
            short8 b0 = *(const short8*)(lrow);
            short8 b1 = *(const short8*)(lrow + 16 * LDS_PXW);
            short8 b2 = *(const short8*)(lrow + 32 * LDS_PXW);
            short8 b3 = *(const short8*)(lrow + 48 * LDS_PXW);
            acc[0][0] = __builtin_amdgcn_mfma_f32_16x16x32_bf16(a0c, b0, acc[0][0], 0, 0, 0);
            acc[1][0] = __builtin_amdgcn_mfma_f32_16x16x32_bf16(a1c, b0, acc[1][0], 0, 0, 0);
            acc[0][1] = __builtin_amdgcn_mfma_f32_16x16x32_bf16(a0c, b1, acc[0][1], 0, 0, 0);
            acc[1][1] = __builtin_amdgcn_mfma_f32_16x16x32_bf16(a1c, b1, acc[1][1], 0, 0, 0);
            acc[0][2] = __builtin_amdgcn_mfma_f32_16x16x32_bf16(a0c, b2, acc[0][2], 0, 0, 0);
            acc[1][2] = __builtin_amdgcn_mfma_f32_16x16x32_bf16(a1c, b2, acc[1][2], 0, 0, 0);
            acc[0][3] = __builtin_amdgcn_mfma_f32_16x16x32_bf16(a0c, b3, acc[0][3], 0, 0, 0);
            acc[1][3] = __builtin_amdgcn_mfma_f32_16x16x32_bf16(a1c, b3, acc[1][3], 0, 0, 0);
            a0c = a0n; a1c = a1n; a0n = a0nn; a1n = a1nn;
        }
        if (it < 7) {
            STAGE_WRITE(cur ^ 1);
            __syncthreads();
            cur ^= 1;
        }
    }

    float* red = (float*)&lds[0][0][0];   // 32 * 256 * 4B = 32,768 B
    __syncthreads();
    if (half == 1) {
#pragma unroll
        for (int m = 0; m < 2; m++)
#pragma unroll
            for (int xs = 0; xs < 4; xs++)
#pragma unroll
                for (int r = 0; r < 4; r++)
                    red[(((m * 4 + xs) * 4) + r) * 256 + th] = acc[m][xs][r];
    }
    __syncthreads();
    if (half == 0) {
#pragma unroll
        for (int m = 0; m < 2; m++) {
#pragma unroll
            for (int r = 0; r < 4; r++) {
                int oc = ocw + m * 16 + lq * 4 + r;
                float bias = cb[oc];
                float* op = out + ((size_t)(n * 256 + oc)) * HW + y0 * 64 + l15;
#pragma unroll
                for (int xs = 0; xs < 4; xs++)
                    op[xs * 16] = acc[m][xs][r] + red[(((m * 4 + xs) * 4) + r) * 256 + th] + bias;
            }
        }
    }
#undef STAGE_LOAD
#undef STAGE_WRITE
#undef SWZ_OFF
}

// ---------------------------------------------------------------------------
extern "C" void kernel_launch(void* const* d_in, const int* in_sizes, int n_in,
                              void* d_out, int out_size, void* d_ws, size_t ws_size,
                              hipStream_t stream) {
    const float* feats  = (const float*)d_in[0];
    const float* Kten   = (const float*)d_in[1];
    const float* Qten   = (const float*)d_in[2];
    const float* w_gap  = (const float*)d_in[3];
    const float* w_gapr = (const float*)d_in[4];
    const float* conv_w = (const float*)d_in[5];
    const float* conv_b = (const float*)d_in[6];
    const int*   label  = (const int*)d_in[7];
    float* ob           = (float*)d_out;

    float* ws = (float*)d_ws;
    float*    mask    = ws;                         // 16384
    unsigned* mmax    = (unsigned*)(ws + 16384);    // 4
    float*    S_f     = ws + 16384 + 4;             // 1024
    float*    S_r     = S_f + 1024;                 // 1024
    float*    att_inf = S_r + 1024;                 // 25*4*16384 = 1,638,400
    float*    Wpl     = att_inf + 1638400;          // 4*4*4096 = 65,536
    float*    att_dif = Wpl + 65536;                // 589,824
    ushort*   xinp    = (ushort*)(att_dif + 589824); // 8,921,088 ushorts
    ushort*   wt3     = xinp + 8921088;              // 1,179,648 ushorts

    const int NXT = N_IMG * C_CH * HW;              // 4,194,304

    // only the halo border needs zeroing; interior rewritten by k_prep_fused
    k_zero_border<<<N_IMG * 260, 256, 0, stream>>>(xinp);

    k_init<<<1, 64, 0, stream>>>(mmax);
    k_mask_m<<<N_IMG * H_DIM, 256, 0, stream>>>(feats, w_gap, label, mask, mmax);
    k_mask_norm<<<64, 256, 0, stream>>>(mask, mmax);

    k_plane_sum<<<N_IMG * C_CH, 256, 0, stream>>>(feats, S_f);
    k_pred<<<1, 128, 0, stream>>>(S_f, w_gap, ob + NXT);

    // infusion(feats, Q, K): scores -> scatter W -> weighted plane sum (GAP swap)
    k_att_inf<<<dim3(N_IMG * H_DIM, NHEADS), 256, 0, stream>>>(Qten, Kten, att_inf);
    k_scatter_w<<<N_IMG * H_DIM, 256, 0, stream>>>(att_inf, Wpl);
    k_wsum<<<N_IMG * C_CH, 256, 0, stream>>>(feats, Wpl, S_r);
    k_pred<<<1, 128, 0, stream>>>(S_r, w_gapr, ob + NXT + N_IMG * NCLASS);

    // diffusion(feats, K, Q): patches from K, center from Q
    k_att_dif<<<N_IMG * H_DIM, 1024, 0, stream>>>(Kten, Qten, mask, att_dif);

    k_prep_w<<<512, 256, 0, stream>>>(conv_w, wt3);
    k_prep_fused<<<dim3(64, 4, 16), 256, 0, stream>>>(feats, mask, att_dif, xinp);

    k_conv_mfma<<<512, 512, 0, stream>>>(xinp, wt3, conv_b, ob);
}